// Round 15
// baseline (278.259 us; speedup 1.0000x reference)
//
#include <hip/hip_runtime.h>
#include <math.h>

#define DD 1024
#define NB 16
#define WSPLIT 4
#define HSPLIT 32

typedef unsigned short u16;
typedef __attribute__((ext_vector_type(8))) short short8;
typedef __attribute__((ext_vector_type(4))) float f32x4;

__device__ __forceinline__ float gelu_f(float x) {
  return 0.5f * x * (1.0f + erff(x * 0.70710678118654752440f));
}
__device__ __forceinline__ u16 f2bf(float f) {
  union { float f; unsigned u; } v; v.f = f;
  return (u16)((v.u + 0x7FFFu + ((v.u >> 16) & 1u)) >> 16);
}
__device__ __forceinline__ float bf2f(u16 b) {
  union { unsigned u; float f; } v; v.u = ((unsigned)b) << 16;
  return v.f;
}
__device__ __forceinline__ void gload_lds16(const u16* g, u16* l) {
  __builtin_amdgcn_global_load_lds(
      (const __attribute__((address_space(1))) void*)g,
      (__attribute__((address_space(3))) void*)l, 16, 0, 0);
}
__device__ __forceinline__ void gload_lds16f(const float* g, float* l) {
  __builtin_amdgcn_global_load_lds(
      (const __attribute__((address_space(1))) void*)g,
      (__attribute__((address_space(3))) void*)l, 16, 0, 0);
}

#define VMCNT8   asm volatile("s_waitcnt vmcnt(8)" ::: "memory")
#define VMCNT4   asm volatile("s_waitcnt vmcnt(4)" ::: "memory")
#define VMCNT0   asm volatile("s_waitcnt vmcnt(0)" ::: "memory")
#define BARRIER  asm volatile("s_barrier" ::: "memory")

// ---- fused prep: cvt x | LN | transpose+cvt base_down | cvt base_up ----
__launch_bounds__(256)
__global__ void prep_kernel(const float* __restrict__ x, u16* __restrict__ xb,
                            const float* __restrict__ ada, const float* __restrict__ gamma,
                            const float* __restrict__ beta, float* __restrict__ c,
                            const float* __restrict__ bdn, u16* __restrict__ bdTb,
                            const float* __restrict__ bu, u16* __restrict__ bub) {
  __shared__ float smem[1056];
  int bid = blockIdx.x;
  int t = threadIdx.x;
  if (bid < 8192) {
    size_t i = (size_t)bid * 256 + t;
    const float4* xf = (const float4*)x;
    float4 v0 = xf[i * 2], v1 = xf[i * 2 + 1];
    short8 o;
    o[0] = (short)f2bf(v0.x); o[1] = (short)f2bf(v0.y);
    o[2] = (short)f2bf(v0.z); o[3] = (short)f2bf(v0.w);
    o[4] = (short)f2bf(v1.x); o[5] = (short)f2bf(v1.y);
    o[6] = (short)f2bf(v1.z); o[7] = (short)f2bf(v1.w);
    *(short8*)(xb + i * 8) = o;
  } else if (bid < 8208) {
    int b = bid - 8192;
    const float* row = ada + b * DD;
    float s = 0.f, s2 = 0.f;
    for (int i = t; i < DD; i += 256) { float v = row[i]; s += v; s2 += v * v; }
    for (int off = 32; off; off >>= 1) { s += __shfl_down(s, off); s2 += __shfl_down(s2, off); }
    float* rs = smem; float* rs2 = smem + 4;
    int wave = t >> 6, lane = t & 63;
    if (lane == 0) { rs[wave] = s; rs2[wave] = s2; }
    __syncthreads();
    if (t == 0) {
      float a = 0.f, a2 = 0.f;
      for (int w = 0; w < 4; w++) { a += rs[w]; a2 += rs2[w]; }
      rs[0] = a * (1.0f / DD); rs2[0] = a2 * (1.0f / DD);
    }
    __syncthreads();
    float mu = rs[0];
    float var = rs2[0] - mu * mu;
    float inv = rsqrtf(var + 1e-5f);
    for (int i = t; i < DD; i += 256)
      c[b * DD + i] = (row[i] - mu) * inv * gamma[i] + beta[i];
  } else if (bid < 9232) {
    int t2 = bid - 8208;
    int bx = (t2 & 31) * 32, by = (t2 >> 5) * 32;
    float (*tile)[33] = (float(*)[33])smem;
    int tx = t & 31, ty = t >> 5;   // 32 x 8
    for (int r = ty; r < 32; r += 8) tile[r][tx] = bdn[(size_t)(by + r) * DD + bx + tx];
    __syncthreads();
    for (int r = ty; r < 32; r += 8)
      bdTb[(size_t)(bx + r) * DD + by + tx] = f2bf(tile[tx][r]);
  } else {
    size_t i = (size_t)(bid - 9232) * 256 + t;
    const float4* bf = (const float4*)bu;
    float4 v0 = bf[i * 2], v1 = bf[i * 2 + 1];
    short8 o;
    o[0] = (short)f2bf(v0.x); o[1] = (short)f2bf(v0.y);
    o[2] = (short)f2bf(v0.z); o[3] = (short)f2bf(v0.w);
    o[4] = (short)f2bf(v1.x); o[5] = (short)f2bf(v1.y);
    o[6] = (short)f2bf(v1.z); o[7] = (short)f2bf(v1.w);
    *(short8*)(bub + i * 8) = o;
  }
}

// ------- h partials: split-K over W1 (32 splits of 32) -------
__launch_bounds__(256)
__global__ void h_part_kernel(const float* __restrict__ c, const float* __restrict__ W1,
                              float* __restrict__ hpart) {
  int s = blockIdx.y;
  int j = blockIdx.x * 256 + threadIdx.x;
  int k0 = s * 32;
  __shared__ float cs[NB][32];
  for (int i = threadIdx.x; i < NB * 32; i += 256)
    cs[i >> 5][i & 31] = c[(size_t)(i >> 5) * DD + k0 + (i & 31)];
  __syncthreads();
  float acc[NB];
  #pragma unroll
  for (int b = 0; b < NB; b++) acc[b] = 0.f;
  #pragma unroll
  for (int al = 0; al < 32; al++) {
    float wv = W1[(size_t)(k0 + al) * DD + j];
    #pragma unroll
    for (int b = 0; b < NB; b++) acc[b] += cs[b][al] * wv;
  }
  #pragma unroll
  for (int b = 0; b < NB; b++)
    hpart[((size_t)s * NB + b) * DD + j] = acc[b];
}

// ------- hT[j][b] = gelu(sum_s hpart[s][b][j] + bias1[j]) (transposed for w_part) -------
__launch_bounds__(256)
__global__ void h_reduce_kernel(const float* __restrict__ hpart, const float* __restrict__ bias1,
                                float* __restrict__ hT) {
  int idx = blockIdx.x * 256 + threadIdx.x;   // b*DD + j
  int b = idx >> 10;
  int j = idx & (DD - 1);
  float acc = bias1[j];
  #pragma unroll
  for (int s = 0; s < HSPLIT; s++) acc += hpart[(size_t)s * NB * DD + idx];
  hT[j * NB + b] = gelu_f(acc);
}

// ------- w partials: LDS-staged W2 stream; h via uniform hT loads (no LDS broadcast) -------
#define WSTAGE(ST, BUF) do { int kr_ = k0 + (ST) * 16;                                      \
    _Pragma("unroll")                                                                       \
    for (int i_ = 0; i_ < 4; i_++)                                                          \
      gload_lds16f(W2 + (size_t)(kr_ + i_ * 4 + (t >> 6)) * 32768 + j0 + ((t & 63) << 2),   \
                   &wlds[BUF][i_ * 4 + (t >> 6)][(t & 63) << 2]);                           \
  } while (0)

__launch_bounds__(256)
__global__ void w_part_kernel(const float* __restrict__ hT, const float* __restrict__ W2,
                              float* __restrict__ part) {
  int s = blockIdx.y;               // 0..3
  int j0 = blockIdx.x * 256;        // f32 col base, grid.x = 128
  int k0 = s * 256;
  int t = threadIdx.x;
  __shared__ __align__(16) float wlds[2][16][256];   // 32 KB, double-buffered W2 tiles

  WSTAGE(0, 0);
  WSTAGE(1, 1);

  float acc[NB] = {};

  #pragma unroll 1
  for (int st = 0; st < 16; st++) {
    if (st < 15) { VMCNT4; } else { VMCNT0; }
    BARRIER;
    int buf = st & 1;
    #pragma unroll
    for (int r = 0; r < 16; r++) {
      float wv = wlds[buf][r][t];
      const f32x4* hp = (const f32x4*)(hT + (size_t)(k0 + st * 16 + r) * NB);  // uniform addr
      f32x4 h0 = hp[0], h1 = hp[1], h2 = hp[2], h3 = hp[3];
      #pragma unroll
      for (int q = 0; q < 4; q++) {
        acc[q]      += h0[q] * wv;
        acc[q + 4]  += h1[q] * wv;
        acc[q + 8]  += h2[q] * wv;
        acc[q + 12] += h3[q] * wv;
      }
    }
    BARRIER;
    if (st + 2 < 16) WSTAGE(st + 2, buf);
  }

  #pragma unroll
  for (int b = 0; b < NB; b++)
    part[((size_t)s * NB + b) * 32768 + j0 + t] = acc[b];
}

// ---- pack_lora: inline w-reduce (bias2 + sum_s part) -> factor panel in LDS,
//      then aext = zero-pad8(src @ colfactor), bext = zero-pad8(rowfactor) ----
//      fac reads vectorized f32x4 (4x fewer LDS instrs than scalar b32).
__launch_bounds__(256)
__global__ void pack_lora_kernel(const u16* __restrict__ src, const float* __restrict__ part,
                                 const float* __restrict__ bias2, int aoff, int boff,
                                 u16* __restrict__ aext, u16* __restrict__ bext) {
  int b = blockIdx.y;
  int t = threadIdx.x;
  int off = (blockIdx.x < 16) ? aoff : boff;
  __shared__ __align__(16) float fac[8192];   // 32 KB: factor [d][r] after reduce
  for (int i = t; i < 8192; i += 256) {
    float acc = bias2[off + i];
    #pragma unroll
    for (int s = 0; s < WSPLIT; s++) acc += part[((size_t)s * NB + b) * 32768 + off + i];
    fac[i] = acc;
  }
  __syncthreads();
  short8 z = {};
  if (blockIdx.x < 16) {
    int row = blockIdx.x * 64 + (t >> 2);
    int q = t & 3;
    const u16* xr = src + ((size_t)b << 20) + (size_t)row * DD + q * 256;
    float acc[8] = {};
    #pragma unroll 2
    for (int kk = 0; kk < 32; kk++) {
      short8 xv = *(const short8*)(xr + kk * 8);
      #pragma unroll
      for (int e = 0; e < 8; e++) {
        float xf = bf2f((u16)xv[e]);
        int d = q * 256 + kk * 8 + e;
        f32x4 f0 = *(const f32x4*)&fac[d * 8];
        f32x4 f1 = *(const f32x4*)&fac[d * 8 + 4];
        acc[0] += xf * f0[0]; acc[1] += xf * f0[1];
        acc[2] += xf * f0[2]; acc[3] += xf * f0[3];
        acc[4] += xf * f1[0]; acc[5] += xf * f1[1];
        acc[6] += xf * f1[2]; acc[7] += xf * f1[3];
      }
    }
    #pragma unroll
    for (int r = 0; r < 8; r++) {
      acc[r] += __shfl_xor(acc[r], 1);
      acc[r] += __shfl_xor(acc[r], 2);
    }
    short8 ov = z;
    if (q == 0) {
      #pragma unroll
      for (int r = 0; r < 8; r++) ov[r] = (short)f2bf(acc[r]);
    }
    u16* orow = aext + ((size_t)b * 1024 + row) * 64 + q * 16;
    *(short8*)orow = ov;
    *(short8*)(orow + 8) = z;
  } else {
    for (int l = t; l < 1024; l += 256) {
      short8 ov;
      #pragma unroll
      for (int r = 0; r < 8; r++) ov[r] = (short)f2bf(fac[l * 8 + r]);
      u16* orow = bext + ((size_t)b * 1024 + l) * 64;
      *(short8*)orow = ov;
      #pragma unroll
      for (int k = 1; k < 8; k++) *(short8*)(orow + k * 8) = z;
    }
  }
}

// ------- batched GEMM 128x128 tile, 4 waves, 2 blocks/CU, counted vmcnt -------
// 16x16x32 MFMA (conflict-free), K = 1024 + 64 (rank-8 ext tile).  grid 1024.
#define STAGE_A(KT, BUF) do { int kt_ = (KT);                                          \
    if (kt_ < 16) { int ks_ = kt_ * 64;                                                \
      _Pragma("unroll")                                                                \
      for (int c_ = 0; c_ < 4; c_++)                                                   \
        gload_lds16(Ab + (size_t)srow[c_] * DD + ks_ + se[c_], As[BUF] + ldsel[c_]);   \
    } else {                                                                           \
      _Pragma("unroll")                                                                \
      for (int c_ = 0; c_ < 4; c_++)                                                   \
        gload_lds16(Ae + (size_t)srow[c_] * 64 + se[c_], As[BUF] + ldsel[c_]);         \
    } } while (0)
#define STAGE_B(KT, BUF) do { int kt_ = (KT);                                          \
    if (kt_ < 16) { int ks_ = kt_ * 64;                                                \
      _Pragma("unroll")                                                                \
      for (int c_ = 0; c_ < 4; c_++)                                                   \
        gload_lds16(Bb + (size_t)srow[c_] * DD + ks_ + se[c_], Bs[BUF] + ldsel[c_]);   \
    } else {                                                                           \
      _Pragma("unroll")                                                                \
      for (int c_ = 0; c_ < 4; c_++)                                                   \
        gload_lds16(Be + (size_t)srow[c_] * 64 + se[c_], Bs[BUF] + ldsel[c_]);         \
    } } while (0)

template<int PHASE>
__launch_bounds__(256, 2)
__global__ void gemm128_kernel(const u16* __restrict__ A, const u16* __restrict__ BT,
                               const u16* __restrict__ Aext, const u16* __restrict__ Bext,
                               const u16* __restrict__ resid, void* __restrict__ Cout) {
  constexpr int BK = 64;
  constexpr int NT = 17;
  __shared__ __align__(16) u16 As[2][128 * BK];   // 32 KB
  __shared__ __align__(16) u16 Bs[2][128 * BK];   // 32 KB

  // Half-batch mapping: each XCD owns one 4tm x 8tn half-batch per round.
  int orig = blockIdx.x;
  int xcd = orig & 7, w = orig >> 3;
  int hb = (w >> 5) * 8 + xcd;
  int tile = w & 31;
  int b = hb >> 1;
  int tm = (hb & 1) * 4 + (tile >> 3);
  int tn = tile & 7;

  const u16* Ab = A + ((size_t)b << 20) + (size_t)(tm * 128) * DD;
  const u16* Bb = BT + (size_t)(tn * 128) * DD;                       // batch-shared
  const u16* Ae = Aext + ((size_t)b * 1024 + tm * 128) * 64;
  const u16* Be = Bext + ((size_t)b * 1024 + tn * 128) * 64;

  int t = threadIdx.x, lane = t & 63, g = lane >> 4, l15 = lane & 15;
  int wave = t >> 6;
  int wm = wave >> 1, wn = wave & 1;           // per-wave 64 x 64 output

  int srow[4], se[4], ldsel[4];
  #pragma unroll
  for (int c = 0; c < 4; c++) {
    int chunk = c * 256 + t;            // 0..1023 -> 16 KB per operand
    srow[c] = chunk >> 3;               // row 0..127
    se[c] = ((chunk & 7) ^ (srow[c] & 7)) << 3;
    ldsel[c] = chunk * 8;
  }

  f32x4 acc[4][4] = {};

  STAGE_A(0, 0); STAGE_B(0, 0);
  STAGE_A(1, 1); STAGE_B(1, 1);
  VMCNT8;
  BARRIER;

  int cur = 0;
  #pragma unroll 1
  for (int kt = 0; kt < NT; kt++) {
    const u16* Ap = As[cur];
    const u16* Bp = Bs[cur];

    #pragma unroll
    for (int kk = 0; kk < 2; kk++) {
      short8 af[4], bf[4];
      #pragma unroll
      for (int i = 0; i < 4; i++) {
        int r = wm * 64 + i * 16 + l15;
        int e = (kk * 32 + g * 8) ^ ((r & 7) << 3);
        af[i] = *(const short8*)(Ap + r * BK + e);
      }
      #pragma unroll
      for (int j = 0; j < 4; j++) {
        int r = wn * 64 + j * 16 + l15;
        int e = (kk * 32 + g * 8) ^ ((r & 7) << 3);
        bf[j] = *(const short8*)(Bp + r * BK + e);
      }
      __builtin_amdgcn_s_setprio(1);
      #pragma unroll
      for (int i = 0; i < 4; i++)
        #pragma unroll
        for (int j = 0; j < 4; j++)
          acc[i][j] = __builtin_amdgcn_mfma_f32_16x16x32_bf16(af[i], bf[j], acc[i][j], 0, 0, 0);
      __builtin_amdgcn_s_setprio(0);
    }

    BARRIER;   // all waves' LDS reads of buf[cur] done (each consumed by MFMA above)
    if (kt + 2 < NT) {
      STAGE_B(kt + 2, cur);
      STAGE_A(kt + 2, cur);
      VMCNT8;  // oldest 8 (= kt+1's) retired -> buf[cur^1] resident
    } else {
      VMCNT0;
    }
    BARRIER;

    cur ^= 1;
  }

  int r0 = tm * 128 + wm * 64, c0 = tn * 128 + wn * 64;
  if (PHASE == 1) {
    u16* mid = (u16*)Cout + ((size_t)b << 20);
    #pragma unroll
    for (int i = 0; i < 4; i++)
      #pragma unroll
      for (int j = 0; j < 4; j++)
        #pragma unroll
        for (int r = 0; r < 4; r++) {
          int row = r0 + i * 16 + g * 4 + r;
          int col = c0 + j * 16 + l15;
          mid[(size_t)row * DD + col] = f2bf(gelu_f(acc[i][j][r]));
        }
  } else {
    float* out = (float*)Cout + ((size_t)b << 20);
    const u16* xb = resid + ((size_t)b << 20);
    #pragma unroll
    for (int i = 0; i < 4; i++)
      #pragma unroll
      for (int j = 0; j < 4; j++)
        #pragma unroll
        for (int r = 0; r < 4; r++) {
          int row = r0 + i * 16 + g * 4 + r;
          int col = c0 + j * 16 + l15;
          size_t idx = (size_t)row * DD + col;
          out[idx] = bf2f(xb[idx]) + acc[i][j][r];
        }
  }
}

extern "C" void kernel_launch(void* const* d_in, const int* in_sizes, int n_in,
                              void* d_out, int out_size, void* d_ws, size_t ws_size,
                              hipStream_t stream) {
  const float* x         = (const float*)d_in[0];
  const float* ada       = (const float*)d_in[1];
  const float* base_up   = (const float*)d_in[2];
  const float* base_down = (const float*)d_in[3];
  const float* gamma     = (const float*)d_in[4];
  const float* beta      = (const float*)d_in[5];
  const float* W1        = (const float*)d_in[6];
  const float* bias1     = (const float*)d_in[7];
  const float* W2        = (const float*)d_in[8];
  const float* bias2     = (const float*)d_in[9];
  float* out = (float*)d_out;
  char* ws = (char*)d_ws;

  float* c     = (float*)(ws);                 // 64 KB
  float* hT    = (float*)(ws + 0x10000);       // 64 KB (transposed h: [j][b])
  u16*   bdTb  = (u16*)  (ws + 0x220000);      // 2 MB
  u16*   bub   = (u16*)  (ws + 0x420000);      // 2 MB
  float* hpart = (float*)(ws + 0x620000);      // 2 MB
  u16*   xb    = (u16*)  (ws + 0x820000);      // 32 MB
  u16*   uext  = (u16*)  (ws + 0x2820000);     // 2 MB
  u16*   b2ext = (u16*)  (ws + 0x2A20000);     // 2 MB
  u16*   vext  = (u16*)  (ws + 0x2C20000);     // 2 MB
  u16*   a1ext = (u16*)  (ws + 0x2E20000);     // 2 MB
  u16*   mid   = (u16*)  (ws + 0x3020000);     // 32 MB
  float* part  = (float*)(ws + 0x5020000);     // 8 MB

  prep_kernel<<<dim3(9744), dim3(256), 0, stream>>>(x, xb, ada, gamma, beta, c,
                                                    base_down, bdTb, base_up, bub);
  h_part_kernel<<<dim3(4, HSPLIT), dim3(256), 0, stream>>>(c, W1, hpart);
  h_reduce_kernel<<<dim3(64), dim3(256), 0, stream>>>(hpart, bias1, hT);
  w_part_kernel<<<dim3(128, WSPLIT), dim3(256), 0, stream>>>(hT, W2, part);
  pack_lora_kernel<<<dim3(17, 16), dim3(256), 0, stream>>>(xb, part, bias2, 16384, 24576,
                                                           uext, b2ext);
  gemm128_kernel<1><<<dim3(1024), dim3(256), 0, stream>>>(xb, bdTb, uext, b2ext,
                                                          (const u16*)nullptr, (void*)mid);
  pack_lora_kernel<<<dim3(17, 16), dim3(256), 0, stream>>>(mid, part, bias2, 8192, 0,
                                                           vext, a1ext);
  gemm128_kernel<2><<<dim3(1024), dim3(256), 0, stream>>>(mid, bub, vext, a1ext, xb, (void*)out);
}

// Round 16
// 269.939 us; speedup vs baseline: 1.0308x; 1.0308x over previous
//
#include <hip/hip_runtime.h>
#include <math.h>

#define DD 1024
#define NB 16
#define WSPLIT 16
#define HSPLIT 32

typedef unsigned short u16;
typedef __attribute__((ext_vector_type(8))) short short8;
typedef __attribute__((ext_vector_type(4))) float f32x4;

__device__ __forceinline__ float gelu_f(float x) {
  return 0.5f * x * (1.0f + erff(x * 0.70710678118654752440f));
}
__device__ __forceinline__ u16 f2bf(float f) {
  union { float f; unsigned u; } v; v.f = f;
  return (u16)((v.u + 0x7FFFu + ((v.u >> 16) & 1u)) >> 16);
}
__device__ __forceinline__ float bf2f(u16 b) {
  union { unsigned u; float f; } v; v.u = ((unsigned)b) << 16;
  return v.f;
}
__device__ __forceinline__ void gload_lds16(const u16* g, u16* l) {
  __builtin_amdgcn_global_load_lds(
      (const __attribute__((address_space(1))) void*)g,
      (__attribute__((address_space(3))) void*)l, 16, 0, 0);
}
__device__ __forceinline__ void gload_lds16f(const float* g, float* l) {
  __builtin_amdgcn_global_load_lds(
      (const __attribute__((address_space(1))) void*)g,
      (__attribute__((address_space(3))) void*)l, 16, 0, 0);
}

#define VMCNT8   asm volatile("s_waitcnt vmcnt(8)" ::: "memory")
#define VMCNT4   asm volatile("s_waitcnt vmcnt(4)" ::: "memory")
#define VMCNT0   asm volatile("s_waitcnt vmcnt(0)" ::: "memory")
#define BARRIER  asm volatile("s_barrier" ::: "memory")

// ---- fused prep: cvt x | LN | transpose+cvt base_down | cvt base_up ----
__launch_bounds__(256)
__global__ void prep_kernel(const float* __restrict__ x, u16* __restrict__ xb,
                            const float* __restrict__ ada, const float* __restrict__ gamma,
                            const float* __restrict__ beta, float* __restrict__ c,
                            const float* __restrict__ bdn, u16* __restrict__ bdTb,
                            const float* __restrict__ bu, u16* __restrict__ bub) {
  __shared__ float smem[1056];
  int bid = blockIdx.x;
  int t = threadIdx.x;
  if (bid < 8192) {
    size_t i = (size_t)bid * 256 + t;
    const float4* xf = (const float4*)x;
    float4 v0 = xf[i * 2], v1 = xf[i * 2 + 1];
    short8 o;
    o[0] = (short)f2bf(v0.x); o[1] = (short)f2bf(v0.y);
    o[2] = (short)f2bf(v0.z); o[3] = (short)f2bf(v0.w);
    o[4] = (short)f2bf(v1.x); o[5] = (short)f2bf(v1.y);
    o[6] = (short)f2bf(v1.z); o[7] = (short)f2bf(v1.w);
    *(short8*)(xb + i * 8) = o;
  } else if (bid < 8208) {
    int b = bid - 8192;
    const float* row = ada + b * DD;
    float s = 0.f, s2 = 0.f;
    for (int i = t; i < DD; i += 256) { float v = row[i]; s += v; s2 += v * v; }
    for (int off = 32; off; off >>= 1) { s += __shfl_down(s, off); s2 += __shfl_down(s2, off); }
    float* rs = smem; float* rs2 = smem + 4;
    int wave = t >> 6, lane = t & 63;
    if (lane == 0) { rs[wave] = s; rs2[wave] = s2; }
    __syncthreads();
    if (t == 0) {
      float a = 0.f, a2 = 0.f;
      for (int w = 0; w < 4; w++) { a += rs[w]; a2 += rs2[w]; }
      rs[0] = a * (1.0f / DD); rs2[0] = a2 * (1.0f / DD);
    }
    __syncthreads();
    float mu = rs[0];
    float var = rs2[0] - mu * mu;
    float inv = rsqrtf(var + 1e-5f);
    for (int i = t; i < DD; i += 256)
      c[b * DD + i] = (row[i] - mu) * inv * gamma[i] + beta[i];
  } else if (bid < 9232) {
    int t2 = bid - 8208;
    int bx = (t2 & 31) * 32, by = (t2 >> 5) * 32;
    float (*tile)[33] = (float(*)[33])smem;
    int tx = t & 31, ty = t >> 5;   // 32 x 8
    for (int r = ty; r < 32; r += 8) tile[r][tx] = bdn[(size_t)(by + r) * DD + bx + tx];
    __syncthreads();
    for (int r = ty; r < 32; r += 8)
      bdTb[(size_t)(bx + r) * DD + by + tx] = f2bf(tile[tx][r]);
  } else {
    size_t i = (size_t)(bid - 9232) * 256 + t;
    const float4* bf = (const float4*)bu;
    float4 v0 = bf[i * 2], v1 = bf[i * 2 + 1];
    short8 o;
    o[0] = (short)f2bf(v0.x); o[1] = (short)f2bf(v0.y);
    o[2] = (short)f2bf(v0.z); o[3] = (short)f2bf(v0.w);
    o[4] = (short)f2bf(v1.x); o[5] = (short)f2bf(v1.y);
    o[6] = (short)f2bf(v1.z); o[7] = (short)f2bf(v1.w);
    *(short8*)(bub + i * 8) = o;
  }
}

// ------- h partials: split-K over W1 (32 splits of 32) -------
__launch_bounds__(256)
__global__ void h_part_kernel(const float* __restrict__ c, const float* __restrict__ W1,
                              float* __restrict__ hpart) {
  int s = blockIdx.y;
  int j = blockIdx.x * 256 + threadIdx.x;
  int k0 = s * 32;
  __shared__ float cs[NB][32];
  for (int i = threadIdx.x; i < NB * 32; i += 256)
    cs[i >> 5][i & 31] = c[(size_t)(i >> 5) * DD + k0 + (i & 31)];
  __syncthreads();
  float acc[NB];
  #pragma unroll
  for (int b = 0; b < NB; b++) acc[b] = 0.f;
  #pragma unroll
  for (int al = 0; al < 32; al++) {
    float wv = W1[(size_t)(k0 + al) * DD + j];
    #pragma unroll
    for (int b = 0; b < NB; b++) acc[b] += cs[b][al] * wv;
  }
  #pragma unroll
  for (int b = 0; b < NB; b++)
    hpart[((size_t)s * NB + b) * DD + j] = acc[b];
}

// ------- h = gelu(sum_s hpart[s] + bias1) -------
__launch_bounds__(256)
__global__ void h_reduce_kernel(const float* __restrict__ hpart, const float* __restrict__ bias1,
                                float* __restrict__ h) {
  int idx = blockIdx.x * 256 + threadIdx.x;
  int j = idx & (DD - 1);
  float acc = bias1[j];
  #pragma unroll
  for (int s = 0; s < HSPLIT; s++) acc += hpart[(size_t)s * NB * DD + idx];
  h[idx] = gelu_f(acc);
}

// ------- w partials: float4 columns/thread, LDS-staged W2, 16 k-splits of 64 -------
// grid (32 j-strips of 1024 f32, 16 splits) = 512 blocks.  Per tile: 4 W2 rows.
#define WSTAGE(ST, BUF) do { int kr_ = k0 + (ST) * 4;                                  \
    _Pragma("unroll")                                                                  \
    for (int c_ = 0; c_ < 4; c_++)                                                     \
      gload_lds16f(W2 + (size_t)(kr_ + c_) * 32768 + j0 + t * 4,                       \
                   &wlds[BUF][c_][t * 4]);                                             \
  } while (0)

__launch_bounds__(256)
__global__ void w_part_kernel(const float* __restrict__ h, const float* __restrict__ W2,
                              float* __restrict__ part) {
  int s = blockIdx.y;               // 0..15
  int j0 = blockIdx.x * 1024;       // f32 col base, grid.x = 32
  int k0 = s * 64;
  int t = threadIdx.x;
  __shared__ __align__(16) float wlds[2][4][1024];   // 32 KB, double-buffered (4 rows/tile)
  __shared__ __align__(16) float hlT[64][17];        // 4.4 KB, h slice [kk][b], pad 17

  // h slice -> LDS transposed (coalesced read; stride-17 write hits all banks)
  #pragma unroll
  for (int v = 0; v < 4; v++) {
    int i = t + v * 256;            // b = i>>6 (0..15), kk = i&63
    hlT[i & 63][i >> 6] = h[(size_t)(i >> 6) * DD + k0 + (i & 63)];
  }

  WSTAGE(0, 0);
  WSTAGE(1, 1);

  f32x4 acc[NB];
  #pragma unroll
  for (int b = 0; b < NB; b++) acc[b] = f32x4{0.f, 0.f, 0.f, 0.f};

  #pragma unroll 1
  for (int st = 0; st < 16; st++) {
    if (st < 15) { VMCNT4; } else { VMCNT0; }   // tile st resident
    BARRIER;                                    // staging + hlT visible
    int buf = st & 1;
    #pragma unroll
    for (int r = 0; r < 4; r++) {
      f32x4 wv = *(const f32x4*)&wlds[buf][r][t * 4];
      int kk = st * 4 + r;
      f32x4 h0 = *(const f32x4*)&hlT[kk][0];
      f32x4 h1 = *(const f32x4*)&hlT[kk][4];
      f32x4 h2 = *(const f32x4*)&hlT[kk][8];
      f32x4 h3 = *(const f32x4*)&hlT[kk][12];
      #pragma unroll
      for (int q = 0; q < 4; q++) {
        acc[q]      += h0[q] * wv;
        acc[q + 4]  += h1[q] * wv;
        acc[q + 8]  += h2[q] * wv;
        acc[q + 12] += h3[q] * wv;
      }
    }
    BARRIER;                                    // all waves done with buf
    if (st + 2 < 16) WSTAGE(st + 2, buf);
  }

  int j4 = blockIdx.x * 256 + t;                // float4 column index
  f32x4* pv = (f32x4*)part;
  #pragma unroll
  for (int b = 0; b < NB; b++)
    pv[((size_t)s * NB + b) * 8192 + j4] = acc[b];
}

// ---- pack_lora: inline w-reduce (bias2 + sum_s part) -> factor panel in LDS,
//      then aext = zero-pad8(src @ colfactor), bext = zero-pad8(rowfactor) ----
__launch_bounds__(256)
__global__ void pack_lora_kernel(const u16* __restrict__ src, const float* __restrict__ part,
                                 const float* __restrict__ bias2, int aoff, int boff,
                                 u16* __restrict__ aext, u16* __restrict__ bext) {
  int b = blockIdx.y;
  int t = threadIdx.x;
  int off = (blockIdx.x < 16) ? aoff : boff;
  __shared__ __align__(16) float fac[8192];   // 32 KB: factor [d][r] after reduce
  for (int i = t; i < 8192; i += 256) {
    float acc = bias2[off + i];
    #pragma unroll
    for (int s = 0; s < WSPLIT; s++) acc += part[((size_t)s * NB + b) * 32768 + off + i];
    fac[i] = acc;
  }
  __syncthreads();
  short8 z = {};
  if (blockIdx.x < 16) {
    int row = blockIdx.x * 64 + (t >> 2);
    int q = t & 3;
    const u16* xr = src + ((size_t)b << 20) + (size_t)row * DD + q * 256;
    float acc[8] = {};
    #pragma unroll 2
    for (int kk = 0; kk < 32; kk++) {
      short8 xv = *(const short8*)(xr + kk * 8);
      #pragma unroll
      for (int e = 0; e < 8; e++) {
        float xf = bf2f((u16)xv[e]);
        int d = q * 256 + kk * 8 + e;
        f32x4 f0 = *(const f32x4*)&fac[d * 8];
        f32x4 f1 = *(const f32x4*)&fac[d * 8 + 4];
        acc[0] += xf * f0[0]; acc[1] += xf * f0[1];
        acc[2] += xf * f0[2]; acc[3] += xf * f0[3];
        acc[4] += xf * f1[0]; acc[5] += xf * f1[1];
        acc[6] += xf * f1[2]; acc[7] += xf * f1[3];
      }
    }
    #pragma unroll
    for (int r = 0; r < 8; r++) {
      acc[r] += __shfl_xor(acc[r], 1);
      acc[r] += __shfl_xor(acc[r], 2);
    }
    short8 ov = z;
    if (q == 0) {
      #pragma unroll
      for (int r = 0; r < 8; r++) ov[r] = (short)f2bf(acc[r]);
    }
    u16* orow = aext + ((size_t)b * 1024 + row) * 64 + q * 16;
    *(short8*)orow = ov;
    *(short8*)(orow + 8) = z;
  } else {
    for (int l = t; l < 1024; l += 256) {
      short8 ov;
      #pragma unroll
      for (int r = 0; r < 8; r++) ov[r] = (short)f2bf(fac[l * 8 + r]);
      u16* orow = bext + ((size_t)b * 1024 + l) * 64;
      *(short8*)orow = ov;
      #pragma unroll
      for (int k = 1; k < 8; k++) *(short8*)(orow + k * 8) = z;
    }
  }
}

// ------- batched GEMM 128x128 tile, 4 waves, 2 blocks/CU, counted vmcnt -------
// 16x16x32 MFMA (conflict-free), K = 1024 + 64 (rank-8 ext tile).  grid 1024.
#define STAGE_A(KT, BUF) do { int kt_ = (KT);                                          \
    if (kt_ < 16) { int ks_ = kt_ * 64;                                                \
      _Pragma("unroll")                                                                \
      for (int c_ = 0; c_ < 4; c_++)                                                   \
        gload_lds16(Ab + (size_t)srow[c_] * DD + ks_ + se[c_], As[BUF] + ldsel[c_]);   \
    } else {                                                                           \
      _Pragma("unroll")                                                                \
      for (int c_ = 0; c_ < 4; c_++)                                                   \
        gload_lds16(Ae + (size_t)srow[c_] * 64 + se[c_], As[BUF] + ldsel[c_]);         \
    } } while (0)
#define STAGE_B(KT, BUF) do { int kt_ = (KT);                                          \
    if (kt_ < 16) { int ks_ = kt_ * 64;                                                \
      _Pragma("unroll")                                                                \
      for (int c_ = 0; c_ < 4; c_++)                                                   \
        gload_lds16(Bb + (size_t)srow[c_] * DD + ks_ + se[c_], Bs[BUF] + ldsel[c_]);   \
    } else {                                                                           \
      _Pragma("unroll")                                                                \
      for (int c_ = 0; c_ < 4; c_++)                                                   \
        gload_lds16(Be + (size_t)srow[c_] * 64 + se[c_], Bs[BUF] + ldsel[c_]);         \
    } } while (0)

template<int PHASE>
__launch_bounds__(256, 2)
__global__ void gemm128_kernel(const u16* __restrict__ A, const u16* __restrict__ BT,
                               const u16* __restrict__ Aext, const u16* __restrict__ Bext,
                               const u16* __restrict__ resid, void* __restrict__ Cout) {
  constexpr int BK = 64;
  constexpr int NT = 17;
  __shared__ __align__(16) u16 As[2][128 * BK];   // 32 KB
  __shared__ __align__(16) u16 Bs[2][128 * BK];   // 32 KB

  // Half-batch mapping: each XCD owns one 4tm x 8tn half-batch per round.
  int orig = blockIdx.x;
  int xcd = orig & 7, w = orig >> 3;
  int hb = (w >> 5) * 8 + xcd;
  int tile = w & 31;
  int b = hb >> 1;
  int tm = (hb & 1) * 4 + (tile >> 3);
  int tn = tile & 7;

  const u16* Ab = A + ((size_t)b << 20) + (size_t)(tm * 128) * DD;
  const u16* Bb = BT + (size_t)(tn * 128) * DD;                       // batch-shared
  const u16* Ae = Aext + ((size_t)b * 1024 + tm * 128) * 64;
  const u16* Be = Bext + ((size_t)b * 1024 + tn * 128) * 64;

  int t = threadIdx.x, lane = t & 63, g = lane >> 4, l15 = lane & 15;
  int wave = t >> 6;
  int wm = wave >> 1, wn = wave & 1;           // per-wave 64 x 64 output

  int srow[4], se[4], ldsel[4];
  #pragma unroll
  for (int c = 0; c < 4; c++) {
    int chunk = c * 256 + t;            // 0..1023 -> 16 KB per operand
    srow[c] = chunk >> 3;               // row 0..127
    se[c] = ((chunk & 7) ^ (srow[c] & 7)) << 3;
    ldsel[c] = chunk * 8;
  }

  f32x4 acc[4][4] = {};

  STAGE_A(0, 0); STAGE_B(0, 0);
  STAGE_A(1, 1); STAGE_B(1, 1);
  VMCNT8;
  BARRIER;

  int cur = 0;
  #pragma unroll 1
  for (int kt = 0; kt < NT; kt++) {
    const u16* Ap = As[cur];
    const u16* Bp = Bs[cur];

    #pragma unroll
    for (int kk = 0; kk < 2; kk++) {
      short8 af[4], bf[4];
      #pragma unroll
      for (int i = 0; i < 4; i++) {
        int r = wm * 64 + i * 16 + l15;
        int e = (kk * 32 + g * 8) ^ ((r & 7) << 3);
        af[i] = *(const short8*)(Ap + r * BK + e);
      }
      #pragma unroll
      for (int j = 0; j < 4; j++) {
        int r = wn * 64 + j * 16 + l15;
        int e = (kk * 32 + g * 8) ^ ((r & 7) << 3);
        bf[j] = *(const short8*)(Bp + r * BK + e);
      }
      __builtin_amdgcn_s_setprio(1);
      #pragma unroll
      for (int i = 0; i < 4; i++)
        #pragma unroll
        for (int j = 0; j < 4; j++)
          acc[i][j] = __builtin_amdgcn_mfma_f32_16x16x32_bf16(af[i], bf[j], acc[i][j], 0, 0, 0);
      __builtin_amdgcn_s_setprio(0);
    }

    BARRIER;   // all waves' LDS reads of buf[cur] done (each consumed by MFMA above)
    if (kt + 2 < NT) {
      STAGE_B(kt + 2, cur);
      STAGE_A(kt + 2, cur);
      VMCNT8;  // oldest 8 (= kt+1's) retired -> buf[cur^1] resident
    } else {
      VMCNT0;
    }
    BARRIER;

    cur ^= 1;
  }

  int r0 = tm * 128 + wm * 64, c0 = tn * 128 + wn * 64;
  if (PHASE == 1) {
    u16* mid = (u16*)Cout + ((size_t)b << 20);
    #pragma unroll
    for (int i = 0; i < 4; i++)
      #pragma unroll
      for (int j = 0; j < 4; j++)
        #pragma unroll
        for (int r = 0; r < 4; r++) {
          int row = r0 + i * 16 + g * 4 + r;
          int col = c0 + j * 16 + l15;
          mid[(size_t)row * DD + col] = f2bf(gelu_f(acc[i][j][r]));
        }
  } else {
    float* out = (float*)Cout + ((size_t)b << 20);
    const u16* xb = resid + ((size_t)b << 20);
    #pragma unroll
    for (int i = 0; i < 4; i++)
      #pragma unroll
      for (int j = 0; j < 4; j++)
        #pragma unroll
        for (int r = 0; r < 4; r++) {
          int row = r0 + i * 16 + g * 4 + r;
          int col = c0 + j * 16 + l15;
          size_t idx = (size_t)row * DD + col;
          out[idx] = bf2f(xb[idx]) + acc[i][j][r];
        }
  }
}

extern "C" void kernel_launch(void* const* d_in, const int* in_sizes, int n_in,
                              void* d_out, int out_size, void* d_ws, size_t ws_size,
                              hipStream_t stream) {
  const float* x         = (const float*)d_in[0];
  const float* ada       = (const float*)d_in[1];
  const float* base_up   = (const float*)d_in[2];
  const float* base_down = (const float*)d_in[3];
  const float* gamma     = (const float*)d_in[4];
  const float* beta      = (const float*)d_in[5];
  const float* W1        = (const float*)d_in[6];
  const float* bias1     = (const float*)d_in[7];
  const float* W2        = (const float*)d_in[8];
  const float* bias2     = (const float*)d_in[9];
  float* out = (float*)d_out;
  char* ws = (char*)d_ws;

  float* c     = (float*)(ws);                 // 64 KB
  float* h     = (float*)(ws + 0x10000);       // 64 KB
  u16*   bdTb  = (u16*)  (ws + 0x220000);      // 2 MB
  u16*   bub   = (u16*)  (ws + 0x420000);      // 2 MB
  float* hpart = (float*)(ws + 0x620000);      // 2 MB
  u16*   xb    = (u16*)  (ws + 0x820000);      // 32 MB
  u16*   uext  = (u16*)  (ws + 0x2820000);     // 2 MB
  u16*   b2ext = (u16*)  (ws + 0x2A20000);     // 2 MB
  u16*   vext  = (u16*)  (ws + 0x2C20000);     // 2 MB
  u16*   a1ext = (u16*)  (ws + 0x2E20000);     // 2 MB
  u16*   mid   = (u16*)  (ws + 0x3020000);     // 32 MB
  float* part  = (float*)(ws + 0x5020000);     // 32 MB

  prep_kernel<<<dim3(9744), dim3(256), 0, stream>>>(x, xb, ada, gamma, beta, c,
                                                    base_down, bdTb, base_up, bub);
  h_part_kernel<<<dim3(4, HSPLIT), dim3(256), 0, stream>>>(c, W1, hpart);
  h_reduce_kernel<<<dim3(64), dim3(256), 0, stream>>>(hpart, bias1, h);
  w_part_kernel<<<dim3(32, WSPLIT), dim3(256), 0, stream>>>(h, W2, part);
  pack_lora_kernel<<<dim3(17, 16), dim3(256), 0, stream>>>(xb, part, bias2, 16384, 24576,
                                                           uext, b2ext);
  gemm128_kernel<1><<<dim3(1024), dim3(256), 0, stream>>>(xb, bdTb, uext, b2ext,
                                                          (const u16*)nullptr, (void*)mid);
  pack_lora_kernel<<<dim3(17, 16), dim3(256), 0, stream>>>(mid, part, bias2, 8192, 0,
                                                           vext, a1ext);
  gemm128_kernel<2><<<dim3(1024), dim3(256), 0, stream>>>(mid, bub, vext, a1ext, xb, (void*)out);
}

// Round 17
// 251.042 us; speedup vs baseline: 1.1084x; 1.0753x over previous
//
#include <hip/hip_runtime.h>
#include <math.h>

#define DD 1024
#define NB 16
#define WSPLIT 8
#define HSPLIT 32

typedef unsigned short u16;
typedef __attribute__((ext_vector_type(8))) short short8;
typedef __attribute__((ext_vector_type(4))) float f32x4;

__device__ __forceinline__ float gelu_f(float x) {
  return 0.5f * x * (1.0f + erff(x * 0.70710678118654752440f));
}
__device__ __forceinline__ u16 f2bf(float f) {
  union { float f; unsigned u; } v; v.f = f;
  return (u16)((v.u + 0x7FFFu + ((v.u >> 16) & 1u)) >> 16);
}
__device__ __forceinline__ float bf2f(u16 b) {
  union { unsigned u; float f; } v; v.u = ((unsigned)b) << 16;
  return v.f;
}
__device__ __forceinline__ void gload_lds16(const u16* g, u16* l) {
  __builtin_amdgcn_global_load_lds(
      (const __attribute__((address_space(1))) void*)g,
      (__attribute__((address_space(3))) void*)l, 16, 0, 0);
}
__device__ __forceinline__ void gload_lds16f(const float* g, float* l) {
  __builtin_amdgcn_global_load_lds(
      (const __attribute__((address_space(1))) void*)g,
      (__attribute__((address_space(3))) void*)l, 16, 0, 0);
}

#define VMCNT8   asm volatile("s_waitcnt vmcnt(8)" ::: "memory")
#define VMCNT4   asm volatile("s_waitcnt vmcnt(4)" ::: "memory")
#define VMCNT0   asm volatile("s_waitcnt vmcnt(0)" ::: "memory")
#define BARRIER  asm volatile("s_barrier" ::: "memory")

// ---- fused prep: cvt x | LN | transpose+cvt base_down | cvt base_up ----
__launch_bounds__(256)
__global__ void prep_kernel(const float* __restrict__ x, u16* __restrict__ xb,
                            const float* __restrict__ ada, const float* __restrict__ gamma,
                            const float* __restrict__ beta, float* __restrict__ c,
                            const float* __restrict__ bdn, u16* __restrict__ bdTb,
                            const float* __restrict__ bu, u16* __restrict__ bub) {
  __shared__ float smem[1056];
  int bid = blockIdx.x;
  int t = threadIdx.x;
  if (bid < 8192) {
    size_t i = (size_t)bid * 256 + t;
    const float4* xf = (const float4*)x;
    float4 v0 = xf[i * 2], v1 = xf[i * 2 + 1];
    short8 o;
    o[0] = (short)f2bf(v0.x); o[1] = (short)f2bf(v0.y);
    o[2] = (short)f2bf(v0.z); o[3] = (short)f2bf(v0.w);
    o[4] = (short)f2bf(v1.x); o[5] = (short)f2bf(v1.y);
    o[6] = (short)f2bf(v1.z); o[7] = (short)f2bf(v1.w);
    *(short8*)(xb + i * 8) = o;
  } else if (bid < 8208) {
    int b = bid - 8192;
    const float* row = ada + b * DD;
    float s = 0.f, s2 = 0.f;
    for (int i = t; i < DD; i += 256) { float v = row[i]; s += v; s2 += v * v; }
    for (int off = 32; off; off >>= 1) { s += __shfl_down(s, off); s2 += __shfl_down(s2, off); }
    float* rs = smem; float* rs2 = smem + 4;
    int wave = t >> 6, lane = t & 63;
    if (lane == 0) { rs[wave] = s; rs2[wave] = s2; }
    __syncthreads();
    if (t == 0) {
      float a = 0.f, a2 = 0.f;
      for (int w = 0; w < 4; w++) { a += rs[w]; a2 += rs2[w]; }
      rs[0] = a * (1.0f / DD); rs2[0] = a2 * (1.0f / DD);
    }
    __syncthreads();
    float mu = rs[0];
    float var = rs2[0] - mu * mu;
    float inv = rsqrtf(var + 1e-5f);
    for (int i = t; i < DD; i += 256)
      c[b * DD + i] = (row[i] - mu) * inv * gamma[i] + beta[i];
  } else if (bid < 9232) {
    int t2 = bid - 8208;
    int bx = (t2 & 31) * 32, by = (t2 >> 5) * 32;
    float (*tile)[33] = (float(*)[33])smem;
    int tx = t & 31, ty = t >> 5;   // 32 x 8
    for (int r = ty; r < 32; r += 8) tile[r][tx] = bdn[(size_t)(by + r) * DD + bx + tx];
    __syncthreads();
    for (int r = ty; r < 32; r += 8)
      bdTb[(size_t)(bx + r) * DD + by + tx] = f2bf(tile[tx][r]);
  } else {
    size_t i = (size_t)(bid - 9232) * 256 + t;
    const float4* bf = (const float4*)bu;
    float4 v0 = bf[i * 2], v1 = bf[i * 2 + 1];
    short8 o;
    o[0] = (short)f2bf(v0.x); o[1] = (short)f2bf(v0.y);
    o[2] = (short)f2bf(v0.z); o[3] = (short)f2bf(v0.w);
    o[4] = (short)f2bf(v1.x); o[5] = (short)f2bf(v1.y);
    o[6] = (short)f2bf(v1.z); o[7] = (short)f2bf(v1.w);
    *(short8*)(bub + i * 8) = o;
  }
}

// ------- h partials: split-K over W1 (32 splits of 32) -------
__launch_bounds__(256)
__global__ void h_part_kernel(const float* __restrict__ c, const float* __restrict__ W1,
                              float* __restrict__ hpart) {
  int s = blockIdx.y;
  int j = blockIdx.x * 256 + threadIdx.x;
  int k0 = s * 32;
  __shared__ float cs[NB][32];
  for (int i = threadIdx.x; i < NB * 32; i += 256)
    cs[i >> 5][i & 31] = c[(size_t)(i >> 5) * DD + k0 + (i & 31)];
  __syncthreads();
  float acc[NB];
  #pragma unroll
  for (int b = 0; b < NB; b++) acc[b] = 0.f;
  #pragma unroll
  for (int al = 0; al < 32; al++) {
    float wv = W1[(size_t)(k0 + al) * DD + j];
    #pragma unroll
    for (int b = 0; b < NB; b++) acc[b] += cs[b][al] * wv;
  }
  #pragma unroll
  for (int b = 0; b < NB; b++)
    hpart[((size_t)s * NB + b) * DD + j] = acc[b];
}

// ------- h = gelu(sum_s hpart[s] + bias1) -------
__launch_bounds__(256)
__global__ void h_reduce_kernel(const float* __restrict__ hpart, const float* __restrict__ bias1,
                                float* __restrict__ h) {
  int idx = blockIdx.x * 256 + threadIdx.x;
  int j = idx & (DD - 1);
  float acc = bias1[j];
  #pragma unroll
  for (int s = 0; s < HSPLIT; s++) acc += hpart[(size_t)s * NB * DD + idx];
  h[idx] = gelu_f(acc);
}

// ------- w partials: float4 columns/thread, LDS-staged W2, 8 k-splits of 128 -------
// grid (32 j-strips of 1024 f32, 8 splits) = 256 blocks = 1/CU.  Per tile: 4 W2 rows.
#define WSTAGE(ST, BUF) do { int kr_ = k0 + (ST) * 4;                                  \
    _Pragma("unroll")                                                                  \
    for (int c_ = 0; c_ < 4; c_++)                                                     \
      gload_lds16f(W2 + (size_t)(kr_ + c_) * 32768 + j0 + t * 4,                       \
                   &wlds[BUF][c_][t * 4]);                                             \
  } while (0)

__launch_bounds__(256)
__global__ void w_part_kernel(const float* __restrict__ h, const float* __restrict__ W2,
                              float* __restrict__ part) {
  int s = blockIdx.y;               // 0..7
  int j0 = blockIdx.x * 1024;       // f32 col base, grid.x = 32
  int k0 = s * 128;
  int t = threadIdx.x;
  __shared__ __align__(16) float wlds[2][4][1024];   // 32 KB, double-buffered (4 rows/tile)
  __shared__ __align__(16) float hlT[128][17];       // 8.7 KB, h slice [kk][b], pad 17

  // h slice -> LDS transposed (coalesced read; stride-17 write hits all banks)
  #pragma unroll
  for (int v = 0; v < 8; v++) {
    int i = t + v * 256;            // b = i>>7 (0..15), kk = i&127
    hlT[i & 127][i >> 7] = h[(size_t)(i >> 7) * DD + k0 + (i & 127)];
  }

  WSTAGE(0, 0);
  WSTAGE(1, 1);

  f32x4 acc[NB];
  #pragma unroll
  for (int b = 0; b < NB; b++) acc[b] = f32x4{0.f, 0.f, 0.f, 0.f};

  #pragma unroll 1
  for (int st = 0; st < 32; st++) {
    if (st < 31) { VMCNT4; } else { VMCNT0; }   // tile st resident
    BARRIER;                                    // staging + hlT visible
    int buf = st & 1;
    #pragma unroll
    for (int r = 0; r < 4; r++) {
      f32x4 wv = *(const f32x4*)&wlds[buf][r][t * 4];
      int kk = st * 4 + r;
      f32x4 h0 = *(const f32x4*)&hlT[kk][0];
      f32x4 h1 = *(const f32x4*)&hlT[kk][4];
      f32x4 h2 = *(const f32x4*)&hlT[kk][8];
      f32x4 h3 = *(const f32x4*)&hlT[kk][12];
      #pragma unroll
      for (int q = 0; q < 4; q++) {
        acc[q]      += h0[q] * wv;
        acc[q + 4]  += h1[q] * wv;
        acc[q + 8]  += h2[q] * wv;
        acc[q + 12] += h3[q] * wv;
      }
    }
    BARRIER;                                    // all waves done with buf
    if (st + 2 < 32) WSTAGE(st + 2, buf);
  }

  int j4 = blockIdx.x * 256 + t;                // float4 column index
  f32x4* pv = (f32x4*)part;
  #pragma unroll
  for (int b = 0; b < NB; b++)
    pv[((size_t)s * NB + b) * 8192 + j4] = acc[b];
}

// ---- pack_lora: inline w-reduce (bias2 + sum_s part) -> factor panel in LDS,
//      then aext = zero-pad8(src @ colfactor), bext = zero-pad8(rowfactor) ----
__launch_bounds__(256)
__global__ void pack_lora_kernel(const u16* __restrict__ src, const float* __restrict__ part,
                                 const float* __restrict__ bias2, int aoff, int boff,
                                 u16* __restrict__ aext, u16* __restrict__ bext) {
  int b = blockIdx.y;
  int t = threadIdx.x;
  int off = (blockIdx.x < 16) ? aoff : boff;
  __shared__ __align__(16) float fac[8192];   // 32 KB: factor [d][r] after reduce
  for (int i = t; i < 8192; i += 256) {
    float acc = bias2[off + i];
    #pragma unroll
    for (int s = 0; s < WSPLIT; s++) acc += part[((size_t)s * NB + b) * 32768 + off + i];
    fac[i] = acc;
  }
  __syncthreads();
  short8 z = {};
  if (blockIdx.x < 16) {
    int row = blockIdx.x * 64 + (t >> 2);
    int q = t & 3;
    const u16* xr = src + ((size_t)b << 20) + (size_t)row * DD + q * 256;
    float acc[8] = {};
    #pragma unroll 2
    for (int kk = 0; kk < 32; kk++) {
      short8 xv = *(const short8*)(xr + kk * 8);
      #pragma unroll
      for (int e = 0; e < 8; e++) {
        float xf = bf2f((u16)xv[e]);
        int d = q * 256 + kk * 8 + e;
        f32x4 f0 = *(const f32x4*)&fac[d * 8];
        f32x4 f1 = *(const f32x4*)&fac[d * 8 + 4];
        acc[0] += xf * f0[0]; acc[1] += xf * f0[1];
        acc[2] += xf * f0[2]; acc[3] += xf * f0[3];
        acc[4] += xf * f1[0]; acc[5] += xf * f1[1];
        acc[6] += xf * f1[2]; acc[7] += xf * f1[3];
      }
    }
    #pragma unroll
    for (int r = 0; r < 8; r++) {
      acc[r] += __shfl_xor(acc[r], 1);
      acc[r] += __shfl_xor(acc[r], 2);
    }
    short8 ov = z;
    if (q == 0) {
      #pragma unroll
      for (int r = 0; r < 8; r++) ov[r] = (short)f2bf(acc[r]);
    }
    u16* orow = aext + ((size_t)b * 1024 + row) * 64 + q * 16;
    *(short8*)orow = ov;
    *(short8*)(orow + 8) = z;
  } else {
    for (int l = t; l < 1024; l += 256) {
      short8 ov;
      #pragma unroll
      for (int r = 0; r < 8; r++) ov[r] = (short)f2bf(fac[l * 8 + r]);
      u16* orow = bext + ((size_t)b * 1024 + l) * 64;
      *(short8*)orow = ov;
      #pragma unroll
      for (int k = 1; k < 8; k++) *(short8*)(orow + k * 8) = z;
    }
  }
}

// ------- batched GEMM 128x128 tile, 4 waves, 2 blocks/CU, counted vmcnt -------
// 16x16x32 MFMA (conflict-free), K = 1024 + 64 (rank-8 ext tile).  grid 1024.
#define STAGE_A(KT, BUF) do { int kt_ = (KT);                                          \
    if (kt_ < 16) { int ks_ = kt_ * 64;                                                \
      _Pragma("unroll")                                                                \
      for (int c_ = 0; c_ < 4; c_++)                                                   \
        gload_lds16(Ab + (size_t)srow[c_] * DD + ks_ + se[c_], As[BUF] + ldsel[c_]);   \
    } else {                                                                           \
      _Pragma("unroll")                                                                \
      for (int c_ = 0; c_ < 4; c_++)                                                   \
        gload_lds16(Ae + (size_t)srow[c_] * 64 + se[c_], As[BUF] + ldsel[c_]);         \
    } } while (0)
#define STAGE_B(KT, BUF) do { int kt_ = (KT);                                          \
    if (kt_ < 16) { int ks_ = kt_ * 64;                                                \
      _Pragma("unroll")                                                                \
      for (int c_ = 0; c_ < 4; c_++)                                                   \
        gload_lds16(Bb + (size_t)srow[c_] * DD + ks_ + se[c_], Bs[BUF] + ldsel[c_]);   \
    } else {                                                                           \
      _Pragma("unroll")                                                                \
      for (int c_ = 0; c_ < 4; c_++)                                                   \
        gload_lds16(Be + (size_t)srow[c_] * 64 + se[c_], Bs[BUF] + ldsel[c_]);         \
    } } while (0)

template<int PHASE>
__launch_bounds__(256, 2)
__global__ void gemm128_kernel(const u16* __restrict__ A, const u16* __restrict__ BT,
                               const u16* __restrict__ Aext, const u16* __restrict__ Bext,
                               const u16* __restrict__ resid, void* __restrict__ Cout) {
  constexpr int BK = 64;
  constexpr int NT = 17;
  __shared__ __align__(16) u16 As[2][128 * BK];   // 32 KB
  __shared__ __align__(16) u16 Bs[2][128 * BK];   // 32 KB

  // Half-batch mapping: each XCD owns one 4tm x 8tn half-batch per round.
  int orig = blockIdx.x;
  int xcd = orig & 7, w = orig >> 3;
  int hb = (w >> 5) * 8 + xcd;
  int tile = w & 31;
  int b = hb >> 1;
  int tm = (hb & 1) * 4 + (tile >> 3);
  int tn = tile & 7;

  const u16* Ab = A + ((size_t)b << 20) + (size_t)(tm * 128) * DD;
  const u16* Bb = BT + (size_t)(tn * 128) * DD;                       // batch-shared
  const u16* Ae = Aext + ((size_t)b * 1024 + tm * 128) * 64;
  const u16* Be = Bext + ((size_t)b * 1024 + tn * 128) * 64;

  int t = threadIdx.x, lane = t & 63, g = lane >> 4, l15 = lane & 15;
  int wave = t >> 6;
  int wm = wave >> 1, wn = wave & 1;           // per-wave 64 x 64 output

  int srow[4], se[4], ldsel[4];
  #pragma unroll
  for (int c = 0; c < 4; c++) {
    int chunk = c * 256 + t;            // 0..1023 -> 16 KB per operand
    srow[c] = chunk >> 3;               // row 0..127
    se[c] = ((chunk & 7) ^ (srow[c] & 7)) << 3;
    ldsel[c] = chunk * 8;
  }

  f32x4 acc[4][4] = {};

  STAGE_A(0, 0); STAGE_B(0, 0);
  STAGE_A(1, 1); STAGE_B(1, 1);
  VMCNT8;
  BARRIER;

  int cur = 0;
  #pragma unroll 1
  for (int kt = 0; kt < NT; kt++) {
    const u16* Ap = As[cur];
    const u16* Bp = Bs[cur];

    #pragma unroll
    for (int kk = 0; kk < 2; kk++) {
      short8 af[4], bf[4];
      #pragma unroll
      for (int i = 0; i < 4; i++) {
        int r = wm * 64 + i * 16 + l15;
        int e = (kk * 32 + g * 8) ^ ((r & 7) << 3);
        af[i] = *(const short8*)(Ap + r * BK + e);
      }
      #pragma unroll
      for (int j = 0; j < 4; j++) {
        int r = wn * 64 + j * 16 + l15;
        int e = (kk * 32 + g * 8) ^ ((r & 7) << 3);
        bf[j] = *(const short8*)(Bp + r * BK + e);
      }
      __builtin_amdgcn_s_setprio(1);
      #pragma unroll
      for (int i = 0; i < 4; i++)
        #pragma unroll
        for (int j = 0; j < 4; j++)
          acc[i][j] = __builtin_amdgcn_mfma_f32_16x16x32_bf16(af[i], bf[j], acc[i][j], 0, 0, 0);
      __builtin_amdgcn_s_setprio(0);
    }

    BARRIER;   // all waves' LDS reads of buf[cur] done (each consumed by MFMA above)
    if (kt + 2 < NT) {
      STAGE_B(kt + 2, cur);
      STAGE_A(kt + 2, cur);
      VMCNT8;  // oldest 8 (= kt+1's) retired -> buf[cur^1] resident
    } else {
      VMCNT0;
    }
    BARRIER;

    cur ^= 1;
  }

  int r0 = tm * 128 + wm * 64, c0 = tn * 128 + wn * 64;
  if (PHASE == 1) {
    u16* mid = (u16*)Cout + ((size_t)b << 20);
    #pragma unroll
    for (int i = 0; i < 4; i++)
      #pragma unroll
      for (int j = 0; j < 4; j++)
        #pragma unroll
        for (int r = 0; r < 4; r++) {
          int row = r0 + i * 16 + g * 4 + r;
          int col = c0 + j * 16 + l15;
          mid[(size_t)row * DD + col] = f2bf(gelu_f(acc[i][j][r]));
        }
  } else {
    float* out = (float*)Cout + ((size_t)b << 20);
    const u16* xb = resid + ((size_t)b << 20);
    #pragma unroll
    for (int i = 0; i < 4; i++)
      #pragma unroll
      for (int j = 0; j < 4; j++)
        #pragma unroll
        for (int r = 0; r < 4; r++) {
          int row = r0 + i * 16 + g * 4 + r;
          int col = c0 + j * 16 + l15;
          size_t idx = (size_t)row * DD + col;
          out[idx] = bf2f(xb[idx]) + acc[i][j][r];
        }
  }
}

extern "C" void kernel_launch(void* const* d_in, const int* in_sizes, int n_in,
                              void* d_out, int out_size, void* d_ws, size_t ws_size,
                              hipStream_t stream) {
  const float* x         = (const float*)d_in[0];
  const float* ada       = (const float*)d_in[1];
  const float* base_up   = (const float*)d_in[2];
  const float* base_down = (const float*)d_in[3];
  const float* gamma     = (const float*)d_in[4];
  const float* beta      = (const float*)d_in[5];
  const float* W1        = (const float*)d_in[6];
  const float* bias1     = (const float*)d_in[7];
  const float* W2        = (const float*)d_in[8];
  const float* bias2     = (const float*)d_in[9];
  float* out = (float*)d_out;
  char* ws = (char*)d_ws;

  float* c     = (float*)(ws);                 // 64 KB
  float* h     = (float*)(ws + 0x10000);       // 64 KB
  u16*   bdTb  = (u16*)  (ws + 0x220000);      // 2 MB
  u16*   bub   = (u16*)  (ws + 0x420000);      // 2 MB
  float* hpart = (float*)(ws + 0x620000);      // 2 MB
  u16*   xb    = (u16*)  (ws + 0x820000);      // 32 MB
  u16*   uext  = (u16*)  (ws + 0x2820000);     // 2 MB
  u16*   b2ext = (u16*)  (ws + 0x2A20000);     // 2 MB
  u16*   vext  = (u16*)  (ws + 0x2C20000);     // 2 MB
  u16*   a1ext = (u16*)  (ws + 0x2E20000);     // 2 MB
  u16*   mid   = (u16*)  (ws + 0x3020000);     // 32 MB
  float* part  = (float*)(ws + 0x5020000);     // 16 MB

  prep_kernel<<<dim3(9744), dim3(256), 0, stream>>>(x, xb, ada, gamma, beta, c,
                                                    base_down, bdTb, base_up, bub);
  h_part_kernel<<<dim3(4, HSPLIT), dim3(256), 0, stream>>>(c, W1, hpart);
  h_reduce_kernel<<<dim3(64), dim3(256), 0, stream>>>(hpart, bias1, h);
  w_part_kernel<<<dim3(32, WSPLIT), dim3(256), 0, stream>>>(h, W2, part);
  pack_lora_kernel<<<dim3(17, 16), dim3(256), 0, stream>>>(xb, part, bias2, 16384, 24576,
                                                           uext, b2ext);
  gemm128_kernel<1><<<dim3(1024), dim3(256), 0, stream>>>(xb, bdTb, uext, b2ext,
                                                          (const u16*)nullptr, (void*)mid);
  pack_lora_kernel<<<dim3(17, 16), dim3(256), 0, stream>>>(mid, part, bias2, 8192, 0,
                                                           vext, a1ext);
  gemm128_kernel<2><<<dim3(1024), dim3(256), 0, stream>>>(mid, bub, vext, a1ext, xb, (void*)out);
}

// Round 18
// 246.497 us; speedup vs baseline: 1.1289x; 1.0184x over previous
//
#include <hip/hip_runtime.h>
#include <math.h>

#define DD 1024
#define NB 16
#define WSPLIT 8
#define HSPLIT 32

typedef unsigned short u16;
typedef __attribute__((ext_vector_type(8))) short short8;
typedef __attribute__((ext_vector_type(4))) float f32x4;

__device__ __forceinline__ float gelu_f(float x) {
  return 0.5f * x * (1.0f + erff(x * 0.70710678118654752440f));
}
__device__ __forceinline__ u16 f2bf(float f) {
  union { float f; unsigned u; } v; v.f = f;
  return (u16)((v.u + 0x7FFFu + ((v.u >> 16) & 1u)) >> 16);
}
__device__ __forceinline__ float bf2f(u16 b) {
  union { unsigned u; float f; } v; v.u = ((unsigned)b) << 16;
  return v.f;
}
__device__ __forceinline__ void gload_lds16(const u16* g, u16* l) {
  __builtin_amdgcn_global_load_lds(
      (const __attribute__((address_space(1))) void*)g,
      (__attribute__((address_space(3))) void*)l, 16, 0, 0);
}
__device__ __forceinline__ void gload_lds16f(const float* g, float* l) {
  __builtin_amdgcn_global_load_lds(
      (const __attribute__((address_space(1))) void*)g,
      (__attribute__((address_space(3))) void*)l, 16, 0, 0);
}

#define VMCNT8   asm volatile("s_waitcnt vmcnt(8)" ::: "memory")
#define VMCNT4   asm volatile("s_waitcnt vmcnt(4)" ::: "memory")
#define VMCNT0   asm volatile("s_waitcnt vmcnt(0)" ::: "memory")
#define BARRIER  asm volatile("s_barrier" ::: "memory")

// ---- fused prep: cvt x | LN | transpose+cvt base_down | cvt base_up ----
__launch_bounds__(256)
__global__ void prep_kernel(const float* __restrict__ x, u16* __restrict__ xb,
                            const float* __restrict__ ada, const float* __restrict__ gamma,
                            const float* __restrict__ beta, float* __restrict__ c,
                            const float* __restrict__ bdn, u16* __restrict__ bdTb,
                            const float* __restrict__ bu, u16* __restrict__ bub) {
  __shared__ float smem[1056];
  int bid = blockIdx.x;
  int t = threadIdx.x;
  if (bid < 8192) {
    size_t i = (size_t)bid * 256 + t;
    const float4* xf = (const float4*)x;
    float4 v0 = xf[i * 2], v1 = xf[i * 2 + 1];
    short8 o;
    o[0] = (short)f2bf(v0.x); o[1] = (short)f2bf(v0.y);
    o[2] = (short)f2bf(v0.z); o[3] = (short)f2bf(v0.w);
    o[4] = (short)f2bf(v1.x); o[5] = (short)f2bf(v1.y);
    o[6] = (short)f2bf(v1.z); o[7] = (short)f2bf(v1.w);
    *(short8*)(xb + i * 8) = o;
  } else if (bid < 8208) {
    int b = bid - 8192;
    const float* row = ada + b * DD;
    float s = 0.f, s2 = 0.f;
    for (int i = t; i < DD; i += 256) { float v = row[i]; s += v; s2 += v * v; }
    for (int off = 32; off; off >>= 1) { s += __shfl_down(s, off); s2 += __shfl_down(s2, off); }
    float* rs = smem; float* rs2 = smem + 4;
    int wave = t >> 6, lane = t & 63;
    if (lane == 0) { rs[wave] = s; rs2[wave] = s2; }
    __syncthreads();
    if (t == 0) {
      float a = 0.f, a2 = 0.f;
      for (int w = 0; w < 4; w++) { a += rs[w]; a2 += rs2[w]; }
      rs[0] = a * (1.0f / DD); rs2[0] = a2 * (1.0f / DD);
    }
    __syncthreads();
    float mu = rs[0];
    float var = rs2[0] - mu * mu;
    float inv = rsqrtf(var + 1e-5f);
    for (int i = t; i < DD; i += 256)
      c[b * DD + i] = (row[i] - mu) * inv * gamma[i] + beta[i];
  } else if (bid < 9232) {
    int t2 = bid - 8208;
    int bx = (t2 & 31) * 32, by = (t2 >> 5) * 32;
    float (*tile)[33] = (float(*)[33])smem;
    int tx = t & 31, ty = t >> 5;   // 32 x 8
    for (int r = ty; r < 32; r += 8) tile[r][tx] = bdn[(size_t)(by + r) * DD + bx + tx];
    __syncthreads();
    for (int r = ty; r < 32; r += 8)
      bdTb[(size_t)(bx + r) * DD + by + tx] = f2bf(tile[tx][r]);
  } else {
    size_t i = (size_t)(bid - 9232) * 256 + t;
    const float4* bf = (const float4*)bu;
    float4 v0 = bf[i * 2], v1 = bf[i * 2 + 1];
    short8 o;
    o[0] = (short)f2bf(v0.x); o[1] = (short)f2bf(v0.y);
    o[2] = (short)f2bf(v0.z); o[3] = (short)f2bf(v0.w);
    o[4] = (short)f2bf(v1.x); o[5] = (short)f2bf(v1.y);
    o[6] = (short)f2bf(v1.z); o[7] = (short)f2bf(v1.w);
    *(short8*)(bub + i * 8) = o;
  }
}

// ------- h partials: split-K over W1 (32 splits of 32) -------
__launch_bounds__(256)
__global__ void h_part_kernel(const float* __restrict__ c, const float* __restrict__ W1,
                              float* __restrict__ hpart) {
  int s = blockIdx.y;
  int j = blockIdx.x * 256 + threadIdx.x;
  int k0 = s * 32;
  __shared__ float cs[NB][32];
  for (int i = threadIdx.x; i < NB * 32; i += 256)
    cs[i >> 5][i & 31] = c[(size_t)(i >> 5) * DD + k0 + (i & 31)];
  __syncthreads();
  float acc[NB];
  #pragma unroll
  for (int b = 0; b < NB; b++) acc[b] = 0.f;
  #pragma unroll
  for (int al = 0; al < 32; al++) {
    float wv = W1[(size_t)(k0 + al) * DD + j];
    #pragma unroll
    for (int b = 0; b < NB; b++) acc[b] += cs[b][al] * wv;
  }
  #pragma unroll
  for (int b = 0; b < NB; b++)
    hpart[((size_t)s * NB + b) * DD + j] = acc[b];
}

// ------- h = gelu(sum_s hpart[s] + bias1) -------
__launch_bounds__(256)
__global__ void h_reduce_kernel(const float* __restrict__ hpart, const float* __restrict__ bias1,
                                float* __restrict__ h) {
  int idx = blockIdx.x * 256 + threadIdx.x;
  int j = idx & (DD - 1);
  float acc = bias1[j];
  #pragma unroll
  for (int s = 0; s < HSPLIT; s++) acc += hpart[(size_t)s * NB * DD + idx];
  h[idx] = gelu_f(acc);
}

// ------- w partials: float4 columns/thread, LDS-staged W2, 8 k-splits of 128 -------
#define WSTAGE(ST, BUF) do { int kr_ = k0 + (ST) * 4;                                  \
    _Pragma("unroll")                                                                  \
    for (int c_ = 0; c_ < 4; c_++)                                                     \
      gload_lds16f(W2 + (size_t)(kr_ + c_) * 32768 + j0 + t * 4,                       \
                   &wlds[BUF][c_][t * 4]);                                             \
  } while (0)

__launch_bounds__(256)
__global__ void w_part_kernel(const float* __restrict__ h, const float* __restrict__ W2,
                              float* __restrict__ part) {
  int s = blockIdx.y;               // 0..7
  int j0 = blockIdx.x * 1024;       // f32 col base, grid.x = 32
  int k0 = s * 128;
  int t = threadIdx.x;
  __shared__ __align__(16) float wlds[2][4][1024];   // 32 KB, double-buffered (4 rows/tile)
  __shared__ __align__(16) float hlT[128][17];       // 8.7 KB, h slice [kk][b], pad 17

  #pragma unroll
  for (int v = 0; v < 8; v++) {
    int i = t + v * 256;            // b = i>>7 (0..15), kk = i&127
    hlT[i & 127][i >> 7] = h[(size_t)(i >> 7) * DD + k0 + (i & 127)];
  }

  WSTAGE(0, 0);
  WSTAGE(1, 1);

  f32x4 acc[NB];
  #pragma unroll
  for (int b = 0; b < NB; b++) acc[b] = f32x4{0.f, 0.f, 0.f, 0.f};

  #pragma unroll 1
  for (int st = 0; st < 32; st++) {
    if (st < 31) { VMCNT4; } else { VMCNT0; }
    BARRIER;
    int buf = st & 1;
    #pragma unroll
    for (int r = 0; r < 4; r++) {
      f32x4 wv = *(const f32x4*)&wlds[buf][r][t * 4];
      int kk = st * 4 + r;
      f32x4 h0 = *(const f32x4*)&hlT[kk][0];
      f32x4 h1 = *(const f32x4*)&hlT[kk][4];
      f32x4 h2 = *(const f32x4*)&hlT[kk][8];
      f32x4 h3 = *(const f32x4*)&hlT[kk][12];
      #pragma unroll
      for (int q = 0; q < 4; q++) {
        acc[q]      += h0[q] * wv;
        acc[q + 4]  += h1[q] * wv;
        acc[q + 8]  += h2[q] * wv;
        acc[q + 12] += h3[q] * wv;
      }
    }
    BARRIER;
    if (st + 2 < 32) WSTAGE(st + 2, buf);
  }

  int j4 = blockIdx.x * 256 + t;
  f32x4* pv = (f32x4*)part;
  #pragma unroll
  for (int b = 0; b < NB; b++)
    pv[((size_t)s * NB + b) * 8192 + j4] = acc[b];
}

// ---- pack_lora: inline w-reduce (f32x4-vectorized) -> factor panel in LDS,
//      then aext = zero-pad8(src @ colfactor), bext = zero-pad8(rowfactor) ----
__launch_bounds__(256)
__global__ void pack_lora_kernel(const u16* __restrict__ src, const float* __restrict__ part,
                                 const float* __restrict__ bias2, int aoff, int boff,
                                 u16* __restrict__ aext, u16* __restrict__ bext) {
  int b = blockIdx.y;
  int t = threadIdx.x;
  int off = (blockIdx.x < 16) ? aoff : boff;   // multiple of 4 elements
  __shared__ __align__(16) float fac[8192];
  {
    const f32x4* bz = (const f32x4*)(bias2 + off);
    #pragma unroll
    for (int i4 = t; i4 < 2048; i4 += 256) {
      f32x4 acc = bz[i4];
      #pragma unroll
      for (int s = 0; s < WSPLIT; s++)
        acc += *(const f32x4*)(part + ((size_t)s * NB + b) * 32768 + off + i4 * 4);
      *(f32x4*)&fac[i4 * 4] = acc;
    }
  }
  __syncthreads();
  short8 z = {};
  if (blockIdx.x < 16) {
    int row = blockIdx.x * 64 + (t >> 2);
    int q = t & 3;
    const u16* xr = src + ((size_t)b << 20) + (size_t)row * DD + q * 256;
    float acc[8] = {};
    #pragma unroll 2
    for (int kk = 0; kk < 32; kk++) {
      short8 xv = *(const short8*)(xr + kk * 8);
      #pragma unroll
      for (int e = 0; e < 8; e++) {
        float xf = bf2f((u16)xv[e]);
        int d = q * 256 + kk * 8 + e;
        f32x4 f0 = *(const f32x4*)&fac[d * 8];
        f32x4 f1 = *(const f32x4*)&fac[d * 8 + 4];
        acc[0] += xf * f0[0]; acc[1] += xf * f0[1];
        acc[2] += xf * f0[2]; acc[3] += xf * f0[3];
        acc[4] += xf * f1[0]; acc[5] += xf * f1[1];
        acc[6] += xf * f1[2]; acc[7] += xf * f1[3];
      }
    }
    #pragma unroll
    for (int r = 0; r < 8; r++) {
      acc[r] += __shfl_xor(acc[r], 1);
      acc[r] += __shfl_xor(acc[r], 2);
    }
    short8 ov = z;
    if (q == 0) {
      #pragma unroll
      for (int r = 0; r < 8; r++) ov[r] = (short)f2bf(acc[r]);
    }
    u16* orow = aext + ((size_t)b * 1024 + row) * 64 + q * 16;
    *(short8*)orow = ov;
    *(short8*)(orow + 8) = z;
  } else {
    for (int l = t; l < 1024; l += 256) {
      short8 ov;
      #pragma unroll
      for (int r = 0; r < 8; r++) ov[r] = (short)f2bf(fac[l * 8 + r]);
      u16* orow = bext + ((size_t)b * 1024 + l) * 64;
      *(short8*)orow = ov;
      #pragma unroll
      for (int k = 1; k < 8; k++) *(short8*)(orow + k * 8) = z;
    }
  }
}

// ------- batched GEMM 128x128 tile, 4 waves, 2 blocks/CU, counted vmcnt -------
// 16x16x32 MFMA, K = 1024 + 64.  K-loop hand-unrolled 2x: STATIC LDS buffers
// (no runtime cur) so all ds_read addresses fold to base-VGPR + imm offset.
#define STAGE_A(KT, BUF) do { int kt_ = (KT);                                          \
    if (kt_ < 16) { int ks_ = kt_ * 64;                                                \
      _Pragma("unroll")                                                                \
      for (int c_ = 0; c_ < 4; c_++)                                                   \
        gload_lds16(Ab + (size_t)srow[c_] * DD + ks_ + se[c_], As[BUF] + ldsel[c_]);   \
    } else {                                                                           \
      _Pragma("unroll")                                                                \
      for (int c_ = 0; c_ < 4; c_++)                                                   \
        gload_lds16(Ae + (size_t)srow[c_] * 64 + se[c_], As[BUF] + ldsel[c_]);         \
    } } while (0)
#define STAGE_B(KT, BUF) do { int kt_ = (KT);                                          \
    if (kt_ < 16) { int ks_ = kt_ * 64;                                                \
      _Pragma("unroll")                                                                \
      for (int c_ = 0; c_ < 4; c_++)                                                   \
        gload_lds16(Bb + (size_t)srow[c_] * DD + ks_ + se[c_], Bs[BUF] + ldsel[c_]);   \
    } else {                                                                           \
      _Pragma("unroll")                                                                \
      for (int c_ = 0; c_ < 4; c_++)                                                   \
        gload_lds16(Be + (size_t)srow[c_] * 64 + se[c_], Bs[BUF] + ldsel[c_]);         \
    } } while (0)

#define GCOMPUTE(BUF) do {                                                             \
    _Pragma("unroll")                                                                  \
    for (int kk = 0; kk < 2; kk++) {                                                   \
      short8 af[4], bf[4];                                                             \
      _Pragma("unroll")                                                                \
      for (int i = 0; i < 4; i++) {                                                    \
        int r = wm * 64 + i * 16 + l15;                                                \
        int e = (kk * 32 + g * 8) ^ ((r & 7) << 3);                                    \
        af[i] = *(const short8*)(As[BUF] + r * BK + e);                                \
      }                                                                                \
      _Pragma("unroll")                                                                \
      for (int j = 0; j < 4; j++) {                                                    \
        int r = wn * 64 + j * 16 + l15;                                                \
        int e = (kk * 32 + g * 8) ^ ((r & 7) << 3);                                    \
        bf[j] = *(const short8*)(Bs[BUF] + r * BK + e);                                \
      }                                                                                \
      __builtin_amdgcn_s_setprio(1);                                                   \
      _Pragma("unroll")                                                                \
      for (int i = 0; i < 4; i++)                                                      \
        _Pragma("unroll")                                                              \
        for (int j = 0; j < 4; j++)                                                    \
          acc[i][j] = __builtin_amdgcn_mfma_f32_16x16x32_bf16(af[i], bf[j],            \
                                                              acc[i][j], 0, 0, 0);     \
      __builtin_amdgcn_s_setprio(0);                                                   \
    } } while (0)

template<int PHASE>
__launch_bounds__(256, 2)
__global__ void gemm128_kernel(const u16* __restrict__ A, const u16* __restrict__ BT,
                               const u16* __restrict__ Aext, const u16* __restrict__ Bext,
                               const u16* __restrict__ resid, void* __restrict__ Cout) {
  constexpr int BK = 64;
  constexpr int NT = 17;
  __shared__ __align__(16) u16 As[2][128 * BK];   // 32 KB
  __shared__ __align__(16) u16 Bs[2][128 * BK];   // 32 KB

  // Half-batch mapping: each XCD owns one 4tm x 8tn half-batch per round.
  int orig = blockIdx.x;
  int xcd = orig & 7, w = orig >> 3;
  int hb = (w >> 5) * 8 + xcd;
  int tile = w & 31;
  int b = hb >> 1;
  int tm = (hb & 1) * 4 + (tile >> 3);
  int tn = tile & 7;

  const u16* Ab = A + ((size_t)b << 20) + (size_t)(tm * 128) * DD;
  const u16* Bb = BT + (size_t)(tn * 128) * DD;                       // batch-shared
  const u16* Ae = Aext + ((size_t)b * 1024 + tm * 128) * 64;
  const u16* Be = Bext + ((size_t)b * 1024 + tn * 128) * 64;

  int t = threadIdx.x, lane = t & 63, g = lane >> 4, l15 = lane & 15;
  int wave = t >> 6;
  int wm = wave >> 1, wn = wave & 1;           // per-wave 64 x 64 output

  int srow[4], se[4], ldsel[4];
  #pragma unroll
  for (int c = 0; c < 4; c++) {
    int chunk = c * 256 + t;            // 0..1023 -> 16 KB per operand
    srow[c] = chunk >> 3;               // row 0..127
    se[c] = ((chunk & 7) ^ (srow[c] & 7)) << 3;
    ldsel[c] = chunk * 8;
  }

  f32x4 acc[4][4] = {};

  STAGE_A(0, 0); STAGE_B(0, 0);
  STAGE_A(1, 1); STAGE_B(1, 1);
  VMCNT8;        // tile 0 resident (tile 1's 8 loads still outstanding)
  BARRIER;

  #pragma unroll 1
  for (int kt2 = 0; kt2 < 16; kt2 += 2) {
    GCOMPUTE(0);                         // tile kt2
    BARRIER;
    STAGE_B(kt2 + 2, 0); STAGE_A(kt2 + 2, 0);   // kt2+2 <= 16 always
    VMCNT8;                              // tile kt2+1's loads complete
    BARRIER;

    GCOMPUTE(1);                         // tile kt2+1
    BARRIER;
    if (kt2 + 3 < NT) {
      STAGE_B(kt2 + 3, 1); STAGE_A(kt2 + 3, 1);
      VMCNT8;                            // tile kt2+2's loads complete
    } else {
      VMCNT0;                            // drain tile 16's loads
    }
    BARRIER;
  }
  GCOMPUTE(0);                           // tile 16

  int r0 = tm * 128 + wm * 64, c0 = tn * 128 + wn * 64;
  if (PHASE == 1) {
    u16* mid = (u16*)Cout + ((size_t)b << 20);
    #pragma unroll
    for (int i = 0; i < 4; i++)
      #pragma unroll
      for (int j = 0; j < 4; j++)
        #pragma unroll
        for (int r = 0; r < 4; r++) {
          int row = r0 + i * 16 + g * 4 + r;
          int col = c0 + j * 16 + l15;
          mid[(size_t)row * DD + col] = f2bf(gelu_f(acc[i][j][r]));
        }
  } else {
    float* out = (float*)Cout + ((size_t)b << 20);
    const u16* xb = resid + ((size_t)b << 20);
    #pragma unroll
    for (int i = 0; i < 4; i++)
      #pragma unroll
      for (int j = 0; j < 4; j++)
        #pragma unroll
        for (int r = 0; r < 4; r++) {
          int row = r0 + i * 16 + g * 4 + r;
          int col = c0 + j * 16 + l15;
          size_t idx = (size_t)row * DD + col;
          out[idx] = bf2f(xb[idx]) + acc[i][j][r];
        }
  }
}

extern "C" void kernel_launch(void* const* d_in, const int* in_sizes, int n_in,
                              void* d_out, int out_size, void* d_ws, size_t ws_size,
                              hipStream_t stream) {
  const float* x         = (const float*)d_in[0];
  const float* ada       = (const float*)d_in[1];
  const float* base_up   = (const float*)d_in[2];
  const float* base_down = (const float*)d_in[3];
  const float* gamma     = (const float*)d_in[4];
  const float* beta      = (const float*)d_in[5];
  const float* W1        = (const float*)d_in[6];
  const float* bias1     = (const float*)d_in[7];
  const float* W2        = (const float*)d_in[8];
  const float* bias2     = (const float*)d_in[9];
  float* out = (float*)d_out;
  char* ws = (char*)d_ws;

  float* c     = (float*)(ws);                 // 64 KB
  float* h     = (float*)(ws + 0x10000);       // 64 KB
  u16*   bdTb  = (u16*)  (ws + 0x220000);      // 2 MB
  u16*   bub   = (u16*)  (ws + 0x420000);      // 2 MB
  float* hpart = (float*)(ws + 0x620000);      // 2 MB
  u16*   xb    = (u16*)  (ws + 0x820000);      // 32 MB
  u16*   uext  = (u16*)  (ws + 0x2820000);     // 2 MB
  u16*   b2ext = (u16*)  (ws + 0x2A20000);     // 2 MB
  u16*   vext  = (u16*)  (ws + 0x2C20000);     // 2 MB
  u16*   a1ext = (u16*)  (ws + 0x2E20000);     // 2 MB
  u16*   mid   = (u16*)  (ws + 0x3020000);     // 32 MB
  float* part  = (float*)(ws + 0x5020000);     // 16 MB

  prep_kernel<<<dim3(9744), dim3(256), 0, stream>>>(x, xb, ada, gamma, beta, c,
                                                    base_down, bdTb, base_up, bub);
  h_part_kernel<<<dim3(4, HSPLIT), dim3(256), 0, stream>>>(c, W1, hpart);
  h_reduce_kernel<<<dim3(64), dim3(256), 0, stream>>>(hpart, bias1, h);
  w_part_kernel<<<dim3(32, WSPLIT), dim3(256), 0, stream>>>(h, W2, part);
  pack_lora_kernel<<<dim3(17, 16), dim3(256), 0, stream>>>(xb, part, bias2, 16384, 24576,
                                                           uext, b2ext);
  gemm128_kernel<1><<<dim3(1024), dim3(256), 0, stream>>>(xb, bdTb, uext, b2ext,
                                                          (const u16*)nullptr, (void*)mid);
  pack_lora_kernel<<<dim3(17, 16), dim3(256), 0, stream>>>(mid, part, bias2, 8192, 0,
                                                           vext, a1ext);
  gemm128_kernel<2><<<dim3(1024), dim3(256), 0, stream>>>(mid, bub, vext, a1ext, xb, (void*)out);
}

// Round 19
// 242.586 us; speedup vs baseline: 1.1471x; 1.0161x over previous
//
#include <hip/hip_runtime.h>
#include <math.h>

#define DD 1024
#define NB 16
#define WSPLIT 8
#define HSPLIT 32

typedef unsigned short u16;
typedef __attribute__((ext_vector_type(8))) short short8;
typedef __attribute__((ext_vector_type(4))) float f32x4;

__device__ __forceinline__ float gelu_f(float x) {
  return 0.5f * x * (1.0f + erff(x * 0.70710678118654752440f));
}
__device__ __forceinline__ u16 f2bf(float f) {
  union { float f; unsigned u; } v; v.f = f;
  return (u16)((v.u + 0x7FFFu + ((v.u >> 16) & 1u)) >> 16);
}
__device__ __forceinline__ float bf2f(u16 b) {
  union { unsigned u; float f; } v; v.u = ((unsigned)b) << 16;
  return v.f;
}
__device__ __forceinline__ void gload_lds16(const u16* g, u16* l) {
  __builtin_amdgcn_global_load_lds(
      (const __attribute__((address_space(1))) void*)g,
      (__attribute__((address_space(3))) void*)l, 16, 0, 0);
}
__device__ __forceinline__ void gload_lds16f(const float* g, float* l) {
  __builtin_amdgcn_global_load_lds(
      (const __attribute__((address_space(1))) void*)g,
      (__attribute__((address_space(3))) void*)l, 16, 0, 0);
}

#define VMCNT4   asm volatile("s_waitcnt vmcnt(4)" ::: "memory")
#define VMCNT0   asm volatile("s_waitcnt vmcnt(0)" ::: "memory")
#define BARRIER  asm volatile("s_barrier" ::: "memory")

// ---- fused prep: cvt x | LN | transpose+cvt base_down | cvt base_up ----
__launch_bounds__(256)
__global__ void prep_kernel(const float* __restrict__ x, u16* __restrict__ xb,
                            const float* __restrict__ ada, const float* __restrict__ gamma,
                            const float* __restrict__ beta, float* __restrict__ c,
                            const float* __restrict__ bdn, u16* __restrict__ bdTb,
                            const float* __restrict__ bu, u16* __restrict__ bub) {
  __shared__ float smem[1056];
  int bid = blockIdx.x;
  int t = threadIdx.x;
  if (bid < 8192) {
    size_t i = (size_t)bid * 256 + t;
    const float4* xf = (const float4*)x;
    float4 v0 = xf[i * 2], v1 = xf[i * 2 + 1];
    short8 o;
    o[0] = (short)f2bf(v0.x); o[1] = (short)f2bf(v0.y);
    o[2] = (short)f2bf(v0.z); o[3] = (short)f2bf(v0.w);
    o[4] = (short)f2bf(v1.x); o[5] = (short)f2bf(v1.y);
    o[6] = (short)f2bf(v1.z); o[7] = (short)f2bf(v1.w);
    *(short8*)(xb + i * 8) = o;
  } else if (bid < 8208) {
    int b = bid - 8192;
    const float* row = ada + b * DD;
    float s = 0.f, s2 = 0.f;
    for (int i = t; i < DD; i += 256) { float v = row[i]; s += v; s2 += v * v; }
    for (int off = 32; off; off >>= 1) { s += __shfl_down(s, off); s2 += __shfl_down(s2, off); }
    float* rs = smem; float* rs2 = smem + 4;
    int wave = t >> 6, lane = t & 63;
    if (lane == 0) { rs[wave] = s; rs2[wave] = s2; }
    __syncthreads();
    if (t == 0) {
      float a = 0.f, a2 = 0.f;
      for (int w = 0; w < 4; w++) { a += rs[w]; a2 += rs2[w]; }
      rs[0] = a * (1.0f / DD); rs2[0] = a2 * (1.0f / DD);
    }
    __syncthreads();
    float mu = rs[0];
    float var = rs2[0] - mu * mu;
    float inv = rsqrtf(var + 1e-5f);
    for (int i = t; i < DD; i += 256)
      c[b * DD + i] = (row[i] - mu) * inv * gamma[i] + beta[i];
  } else if (bid < 9232) {
    int t2 = bid - 8208;
    int bx = (t2 & 31) * 32, by = (t2 >> 5) * 32;
    float (*tile)[33] = (float(*)[33])smem;
    int tx = t & 31, ty = t >> 5;   // 32 x 8
    for (int r = ty; r < 32; r += 8) tile[r][tx] = bdn[(size_t)(by + r) * DD + bx + tx];
    __syncthreads();
    for (int r = ty; r < 32; r += 8)
      bdTb[(size_t)(bx + r) * DD + by + tx] = f2bf(tile[tx][r]);
  } else {
    size_t i = (size_t)(bid - 9232) * 256 + t;
    const float4* bf = (const float4*)bu;
    float4 v0 = bf[i * 2], v1 = bf[i * 2 + 1];
    short8 o;
    o[0] = (short)f2bf(v0.x); o[1] = (short)f2bf(v0.y);
    o[2] = (short)f2bf(v0.z); o[3] = (short)f2bf(v0.w);
    o[4] = (short)f2bf(v1.x); o[5] = (short)f2bf(v1.y);
    o[6] = (short)f2bf(v1.z); o[7] = (short)f2bf(v1.w);
    *(short8*)(bub + i * 8) = o;
  }
}

// ------- h partials: split-K over W1 (32 splits of 32) -------
__launch_bounds__(256)
__global__ void h_part_kernel(const float* __restrict__ c, const float* __restrict__ W1,
                              float* __restrict__ hpart) {
  int s = blockIdx.y;
  int j = blockIdx.x * 256 + threadIdx.x;
  int k0 = s * 32;
  __shared__ float cs[NB][32];
  for (int i = threadIdx.x; i < NB * 32; i += 256)
    cs[i >> 5][i & 31] = c[(size_t)(i >> 5) * DD + k0 + (i & 31)];
  __syncthreads();
  float acc[NB];
  #pragma unroll
  for (int b = 0; b < NB; b++) acc[b] = 0.f;
  #pragma unroll
  for (int al = 0; al < 32; al++) {
    float wv = W1[(size_t)(k0 + al) * DD + j];
    #pragma unroll
    for (int b = 0; b < NB; b++) acc[b] += cs[b][al] * wv;
  }
  #pragma unroll
  for (int b = 0; b < NB; b++)
    hpart[((size_t)s * NB + b) * DD + j] = acc[b];
}

// ------- h = gelu(sum_s hpart[s] + bias1) -------
__launch_bounds__(256)
__global__ void h_reduce_kernel(const float* __restrict__ hpart, const float* __restrict__ bias1,
                                float* __restrict__ h) {
  int idx = blockIdx.x * 256 + threadIdx.x;
  int j = idx & (DD - 1);
  float acc = bias1[j];
  #pragma unroll
  for (int s = 0; s < HSPLIT; s++) acc += hpart[(size_t)s * NB * DD + idx];
  h[idx] = gelu_f(acc);
}

// ------- w partials: float4 columns/thread, LDS-staged W2, 8 k-splits of 128 -------
#define WSTAGE(ST, BUF) do { int kr_ = k0 + (ST) * 4;                                  \
    _Pragma("unroll")                                                                  \
    for (int c_ = 0; c_ < 4; c_++)                                                     \
      gload_lds16f(W2 + (size_t)(kr_ + c_) * 32768 + j0 + t * 4,                       \
                   &wlds[BUF][c_][t * 4]);                                             \
  } while (0)

__launch_bounds__(256)
__global__ void w_part_kernel(const float* __restrict__ h, const float* __restrict__ W2,
                              float* __restrict__ part) {
  int s = blockIdx.y;               // 0..7
  int j0 = blockIdx.x * 1024;       // f32 col base, grid.x = 32
  int k0 = s * 128;
  int t = threadIdx.x;
  __shared__ __align__(16) float wlds[2][4][1024];   // 32 KB, double-buffered (4 rows/tile)
  __shared__ __align__(16) float hlT[128][17];       // 8.7 KB, h slice [kk][b], pad 17

  #pragma unroll
  for (int v = 0; v < 8; v++) {
    int i = t + v * 256;            // b = i>>7 (0..15), kk = i&127
    hlT[i & 127][i >> 7] = h[(size_t)(i >> 7) * DD + k0 + (i & 127)];
  }

  WSTAGE(0, 0);
  WSTAGE(1, 1);

  f32x4 acc[NB];
  #pragma unroll
  for (int b = 0; b < NB; b++) acc[b] = f32x4{0.f, 0.f, 0.f, 0.f};

  #pragma unroll 1
  for (int st = 0; st < 32; st++) {
    if (st < 31) { VMCNT4; } else { VMCNT0; }
    BARRIER;
    int buf = st & 1;
    #pragma unroll
    for (int r = 0; r < 4; r++) {
      f32x4 wv = *(const f32x4*)&wlds[buf][r][t * 4];
      int kk = st * 4 + r;
      f32x4 h0 = *(const f32x4*)&hlT[kk][0];
      f32x4 h1 = *(const f32x4*)&hlT[kk][4];
      f32x4 h2 = *(const f32x4*)&hlT[kk][8];
      f32x4 h3 = *(const f32x4*)&hlT[kk][12];
      #pragma unroll
      for (int q = 0; q < 4; q++) {
        acc[q]      += h0[q] * wv;
        acc[q + 4]  += h1[q] * wv;
        acc[q + 8]  += h2[q] * wv;
        acc[q + 12] += h3[q] * wv;
      }
    }
    BARRIER;
    if (st + 2 < 32) WSTAGE(st + 2, buf);
  }

  int j4 = blockIdx.x * 256 + t;
  f32x4* pv = (f32x4*)part;
  #pragma unroll
  for (int b = 0; b < NB; b++)
    pv[((size_t)s * NB + b) * 8192 + j4] = acc[b];
}

// ---- pack_lora: inline w-reduce (f32x4-vectorized) -> factor panel in LDS,
//      then aext = zero-pad8(src @ colfactor), bext = zero-pad8(rowfactor) ----
__launch_bounds__(256)
__global__ void pack_lora_kernel(const u16* __restrict__ src, const float* __restrict__ part,
                                 const float* __restrict__ bias2, int aoff, int boff,
                                 u16* __restrict__ aext, u16* __restrict__ bext) {
  int b = blockIdx.y;
  int t = threadIdx.x;
  int off = (blockIdx.x < 16) ? aoff : boff;   // multiple of 4 elements
  __shared__ __align__(16) float fac[8192];
  {
    const f32x4* bz = (const f32x4*)(bias2 + off);
    #pragma unroll
    for (int i4 = t; i4 < 2048; i4 += 256) {
      f32x4 acc = bz[i4];
      #pragma unroll
      for (int s = 0; s < WSPLIT; s++)
        acc += *(const f32x4*)(part + ((size_t)s * NB + b) * 32768 + off + i4 * 4);
      *(f32x4*)&fac[i4 * 4] = acc;
    }
  }
  __syncthreads();
  short8 z = {};
  if (blockIdx.x < 16) {
    int row = blockIdx.x * 64 + (t >> 2);
    int q = t & 3;
    const u16* xr = src + ((size_t)b << 20) + (size_t)row * DD + q * 256;
    float acc[8] = {};
    #pragma unroll 2
    for (int kk = 0; kk < 32; kk++) {
      short8 xv = *(const short8*)(xr + kk * 8);
      #pragma unroll
      for (int e = 0; e < 8; e++) {
        float xf = bf2f((u16)xv[e]);
        int d = q * 256 + kk * 8 + e;
        f32x4 f0 = *(const f32x4*)&fac[d * 8];
        f32x4 f1 = *(const f32x4*)&fac[d * 8 + 4];
        acc[0] += xf * f0[0]; acc[1] += xf * f0[1];
        acc[2] += xf * f0[2]; acc[3] += xf * f0[3];
        acc[4] += xf * f1[0]; acc[5] += xf * f1[1];
        acc[6] += xf * f1[2]; acc[7] += xf * f1[3];
      }
    }
    #pragma unroll
    for (int r = 0; r < 8; r++) {
      acc[r] += __shfl_xor(acc[r], 1);
      acc[r] += __shfl_xor(acc[r], 2);
    }
    short8 ov = z;
    if (q == 0) {
      #pragma unroll
      for (int r = 0; r < 8; r++) ov[r] = (short)f2bf(acc[r]);
    }
    u16* orow = aext + ((size_t)b * 1024 + row) * 64 + q * 16;
    *(short8*)orow = ov;
    *(short8*)(orow + 8) = z;
  } else {
    for (int l = t; l < 1024; l += 256) {
      short8 ov;
      #pragma unroll
      for (int r = 0; r < 8; r++) ov[r] = (short)f2bf(fac[l * 8 + r]);
      u16* orow = bext + ((size_t)b * 1024 + l) * 64;
      *(short8*)orow = ov;
      #pragma unroll
      for (int k = 1; k < 8; k++) *(short8*)(orow + k * 8) = z;
    }
  }
}

// ------- batched GEMM 128x128 tile, 4 waves, m97 structure: single-buffer LDS,
// vmcnt(0)+barrier per K-tile, 4 blocks/CU residency (cross-block overlap hides
// the drain).  16x16x32 MFMA, K = 1024 + 64 (rank-8 ext tile).  grid 1024.
#define STAGE_A(KT) do { int kt_ = (KT);                                               \
    if (kt_ < 16) { int ks_ = kt_ * 64;                                                \
      _Pragma("unroll")                                                                \
      for (int c_ = 0; c_ < 4; c_++)                                                   \
        gload_lds16(Ab + (size_t)srow[c_] * DD + ks_ + se[c_], As + ldsel[c_]);        \
    } else {                                                                           \
      _Pragma("unroll")                                                                \
      for (int c_ = 0; c_ < 4; c_++)                                                   \
        gload_lds16(Ae + (size_t)srow[c_] * 64 + se[c_], As + ldsel[c_]);              \
    } } while (0)
#define STAGE_B(KT) do { int kt_ = (KT);                                               \
    if (kt_ < 16) { int ks_ = kt_ * 64;                                                \
      _Pragma("unroll")                                                                \
      for (int c_ = 0; c_ < 4; c_++)                                                   \
        gload_lds16(Bb + (size_t)srow[c_] * DD + ks_ + se[c_], Bs + ldsel[c_]);        \
    } else {                                                                           \
      _Pragma("unroll")                                                                \
      for (int c_ = 0; c_ < 4; c_++)                                                   \
        gload_lds16(Be + (size_t)srow[c_] * 64 + se[c_], Bs + ldsel[c_]);              \
    } } while (0)

template<int PHASE>
__launch_bounds__(256, 4)
__global__ void gemm128_kernel(const u16* __restrict__ A, const u16* __restrict__ BT,
                               const u16* __restrict__ Aext, const u16* __restrict__ Bext,
                               const u16* __restrict__ resid, void* __restrict__ Cout) {
  constexpr int BK = 64;
  constexpr int NT = 17;
  __shared__ __align__(16) u16 As[128 * BK];   // 16 KB
  __shared__ __align__(16) u16 Bs[128 * BK];   // 16 KB  (32 KB total -> 4 blocks/CU)

  // Half-batch mapping: each XCD owns one 4tm x 8tn half-batch per round.
  int orig = blockIdx.x;
  int xcd = orig & 7, w = orig >> 3;
  int hb = (w >> 5) * 8 + xcd;
  int tile = w & 31;
  int b = hb >> 1;
  int tm = (hb & 1) * 4 + (tile >> 3);
  int tn = tile & 7;

  const u16* Ab = A + ((size_t)b << 20) + (size_t)(tm * 128) * DD;
  const u16* Bb = BT + (size_t)(tn * 128) * DD;                       // batch-shared
  const u16* Ae = Aext + ((size_t)b * 1024 + tm * 128) * 64;
  const u16* Be = Bext + ((size_t)b * 1024 + tn * 128) * 64;

  int t = threadIdx.x, lane = t & 63, g = lane >> 4, l15 = lane & 15;
  int wave = t >> 6;
  int wm = wave >> 1, wn = wave & 1;           // per-wave 64 x 64 output

  int srow[4], se[4], ldsel[4];
  #pragma unroll
  for (int c = 0; c < 4; c++) {
    int chunk = c * 256 + t;            // 0..1023 -> 16 KB per operand
    srow[c] = chunk >> 3;               // row 0..127
    se[c] = ((chunk & 7) ^ (srow[c] & 7)) << 3;
    ldsel[c] = chunk * 8;
  }

  f32x4 acc[4][4] = {};

  #pragma unroll 1
  for (int kt = 0; kt < NT; kt++) {
    STAGE_A(kt); STAGE_B(kt);
    VMCNT0;
    BARRIER;
    #pragma unroll
    for (int kk = 0; kk < 2; kk++) {
      short8 af[4], bf[4];
      #pragma unroll
      for (int i = 0; i < 4; i++) {
        int r = wm * 64 + i * 16 + l15;
        int e = (kk * 32 + g * 8) ^ ((r & 7) << 3);
        af[i] = *(const short8*)(As + r * BK + e);
      }
      #pragma unroll
      for (int j = 0; j < 4; j++) {
        int r = wn * 64 + j * 16 + l15;
        int e = (kk * 32 + g * 8) ^ ((r & 7) << 3);
        bf[j] = *(const short8*)(Bs + r * BK + e);
      }
      __builtin_amdgcn_s_setprio(1);
      #pragma unroll
      for (int i = 0; i < 4; i++)
        #pragma unroll
        for (int j = 0; j < 4; j++)
          acc[i][j] = __builtin_amdgcn_mfma_f32_16x16x32_bf16(af[i], bf[j], acc[i][j], 0, 0, 0);
      __builtin_amdgcn_s_setprio(0);
    }
    BARRIER;   // all waves' LDS reads done -> safe to overwrite next iteration
  }

  int r0 = tm * 128 + wm * 64, c0 = tn * 128 + wn * 64;
  if (PHASE == 1) {
    u16* mid = (u16*)Cout + ((size_t)b << 20);
    #pragma unroll
    for (int i = 0; i < 4; i++)
      #pragma unroll
      for (int j = 0; j < 4; j++)
        #pragma unroll
        for (int r = 0; r < 4; r++) {
          int row = r0 + i * 16 + g * 4 + r;
          int col = c0 + j * 16 + l15;
          mid[(size_t)row * DD + col] = f2bf(gelu_f(acc[i][j][r]));
        }
  } else {
    float* out = (float*)Cout + ((size_t)b << 20);
    const u16* xb = resid + ((size_t)b << 20);
    #pragma unroll
    for (int i = 0; i < 4; i++)
      #pragma unroll
      for (int j = 0; j < 4; j++)
        #pragma unroll
        for (int r = 0; r < 4; r++) {
          int row = r0 + i * 16 + g * 4 + r;
          int col = c0 + j * 16 + l15;
          size_t idx = (size_t)row * DD + col;
          out[idx] = bf2f(xb[idx]) + acc[i][j][r];
        }
  }
}

extern "C" void kernel_launch(void* const* d_in, const int* in_sizes, int n_in,
                              void* d_out, int out_size, void* d_ws, size_t ws_size,
                              hipStream_t stream) {
  const float* x         = (const float*)d_in[0];
  const float* ada       = (const float*)d_in[1];
  const float* base_up   = (const float*)d_in[2];
  const float* base_down = (const float*)d_in[3];
  const float* gamma     = (const float*)d_in[4];
  const float* beta      = (const float*)d_in[5];
  const float* W1        = (const float*)d_in[6];
  const float* bias1     = (const float*)d_in[7];
  const float* W2        = (const float*)d_in[8];
  const float* bias2     = (const float*)d_in[9];
  float* out = (float*)d_out;
  char* ws = (char*)d_ws;

  float* c     = (float*)(ws);                 // 64 KB
  float* h     = (float*)(ws + 0x10000);       // 64 KB
  u16*   bdTb  = (u16*)  (ws + 0x220000);      // 2 MB
  u16*   bub   = (u16*)  (ws + 0x420000);      // 2 MB
  float* hpart = (float*)(ws + 0x620000);      // 2 MB
  u16*   xb    = (u16*)  (ws + 0x820000);      // 32 MB
  u16*   uext  = (u16*)  (ws + 0x2820000);     // 2 MB
  u16*   b2ext = (u16*)  (ws + 0x2A20000);     // 2 MB
  u16*   vext  = (u16*)  (ws + 0x2C20000);     // 2 MB
  u16*   a1ext = (u16*)  (ws + 0x2E20000);     // 2 MB
  u16*   mid   = (u16*)  (ws + 0x3020000);     // 32 MB
  float* part  = (float*)(ws + 0x5020000);     // 16 MB

  prep_kernel<<<dim3(9744), dim3(256), 0, stream>>>(x, xb, ada, gamma, beta, c,
                                                    base_down, bdTb, base_up, bub);
  h_part_kernel<<<dim3(4, HSPLIT), dim3(256), 0, stream>>>(c, W1, hpart);
  h_reduce_kernel<<<dim3(64), dim3(256), 0, stream>>>(hpart, bias1, h);
  w_part_kernel<<<dim3(32, WSPLIT), dim3(256), 0, stream>>>(h, W2, part);
  pack_lora_kernel<<<dim3(17, 16), dim3(256), 0, stream>>>(xb, part, bias2, 16384, 24576,
                                                           uext, b2ext);
  gemm128_kernel<1><<<dim3(1024), dim3(256), 0, stream>>>(xb, bdTb, uext, b2ext,
                                                          (const u16*)nullptr, (void*)mid);
  pack_lora_kernel<<<dim3(17, 16), dim3(256), 0, stream>>>(mid, part, bias2, 8192, 0,
                                                           vext, a1ext);
  gemm128_kernel<2><<<dim3(1024), dim3(256), 0, stream>>>(mid, bub, vext, a1ext, xb, (void*)out);
}

// Round 20
// 235.624 us; speedup vs baseline: 1.1809x; 1.0295x over previous
//
#include <hip/hip_runtime.h>
#include <math.h>

#define DD 1024
#define NB 16
#define WSPLIT 8
#define HSPLIT 32

typedef unsigned short u16;
typedef __attribute__((ext_vector_type(4))) short short4v;
typedef __attribute__((ext_vector_type(8))) short short8;
typedef __attribute__((ext_vector_type(4))) float f32x4;

__device__ __forceinline__ float gelu_f(float x) {
  return 0.5f * x * (1.0f + erff(x * 0.70710678118654752440f));
}
__device__ __forceinline__ u16 f2bf(float f) {
  union { float f; unsigned u; } v; v.f = f;
  return (u16)((v.u + 0x7FFFu + ((v.u >> 16) & 1u)) >> 16);
}
__device__ __forceinline__ float bf2f(u16 b) {
  union { unsigned u; float f; } v; v.u = ((unsigned)b) << 16;
  return v.f;
}
__device__ __forceinline__ void gload_lds16(const u16* g, u16* l) {
  __builtin_amdgcn_global_load_lds(
      (const __attribute__((address_space(1))) void*)g,
      (__attribute__((address_space(3))) void*)l, 16, 0, 0);
}
__device__ __forceinline__ void gload_lds16f(const float* g, float* l) {
  __builtin_amdgcn_global_load_lds(
      (const __attribute__((address_space(1))) void*)g,
      (__attribute__((address_space(3))) void*)l, 16, 0, 0);
}

#define VMCNT4   asm volatile("s_waitcnt vmcnt(4)" ::: "memory")
#define VMCNT0   asm volatile("s_waitcnt vmcnt(0)" ::: "memory")
#define BARRIER  asm volatile("s_barrier" ::: "memory")

// ---- fused prep: cvt x | LN | transpose+cvt base_down | cvt base_up ----
__launch_bounds__(256)
__global__ void prep_kernel(const float* __restrict__ x, u16* __restrict__ xb,
                            const float* __restrict__ ada, const float* __restrict__ gamma,
                            const float* __restrict__ beta, float* __restrict__ c,
                            const float* __restrict__ bdn, u16* __restrict__ bdTb,
                            const float* __restrict__ bu, u16* __restrict__ bub) {
  __shared__ float smem[1056];
  int bid = blockIdx.x;
  int t = threadIdx.x;
  if (bid < 8192) {
    size_t i = (size_t)bid * 256 + t;
    const float4* xf = (const float4*)x;
    float4 v0 = xf[i * 2], v1 = xf[i * 2 + 1];
    short8 o;
    o[0] = (short)f2bf(v0.x); o[1] = (short)f2bf(v0.y);
    o[2] = (short)f2bf(v0.z); o[3] = (short)f2bf(v0.w);
    o[4] = (short)f2bf(v1.x); o[5] = (short)f2bf(v1.y);
    o[6] = (short)f2bf(v1.z); o[7] = (short)f2bf(v1.w);
    *(short8*)(xb + i * 8) = o;
  } else if (bid < 8208) {
    int b = bid - 8192;
    const float* row = ada + b * DD;
    float s = 0.f, s2 = 0.f;
    for (int i = t; i < DD; i += 256) { float v = row[i]; s += v; s2 += v * v; }
    for (int off = 32; off; off >>= 1) { s += __shfl_down(s, off); s2 += __shfl_down(s2, off); }
    float* rs = smem; float* rs2 = smem + 4;
    int wave = t >> 6, lane = t & 63;
    if (lane == 0) { rs[wave] = s; rs2[wave] = s2; }
    __syncthreads();
    if (t == 0) {
      float a = 0.f, a2 = 0.f;
      for (int w = 0; w < 4; w++) { a += rs[w]; a2 += rs2[w]; }
      rs[0] = a * (1.0f / DD); rs2[0] = a2 * (1.0f / DD);
    }
    __syncthreads();
    float mu = rs[0];
    float var = rs2[0] - mu * mu;
    float inv = rsqrtf(var + 1e-5f);
    for (int i = t; i < DD; i += 256)
      c[b * DD + i] = (row[i] - mu) * inv * gamma[i] + beta[i];
  } else if (bid < 9232) {
    int t2 = bid - 8208;
    int bx = (t2 & 31) * 32, by = (t2 >> 5) * 32;
    float (*tile)[33] = (float(*)[33])smem;
    int tx = t & 31, ty = t >> 5;   // 32 x 8
    for (int r = ty; r < 32; r += 8) tile[r][tx] = bdn[(size_t)(by + r) * DD + bx + tx];
    __syncthreads();
    for (int r = ty; r < 32; r += 8)
      bdTb[(size_t)(bx + r) * DD + by + tx] = f2bf(tile[tx][r]);
  } else {
    size_t i = (size_t)(bid - 9232) * 256 + t;
    const float4* bf = (const float4*)bu;
    float4 v0 = bf[i * 2], v1 = bf[i * 2 + 1];
    short8 o;
    o[0] = (short)f2bf(v0.x); o[1] = (short)f2bf(v0.y);
    o[2] = (short)f2bf(v0.z); o[3] = (short)f2bf(v0.w);
    o[4] = (short)f2bf(v1.x); o[5] = (short)f2bf(v1.y);
    o[6] = (short)f2bf(v1.z); o[7] = (short)f2bf(v1.w);
    *(short8*)(bub + i * 8) = o;
  }
}

// ------- h partials: split-K over W1 (32 splits of 32) -------
__launch_bounds__(256)
__global__ void h_part_kernel(const float* __restrict__ c, const float* __restrict__ W1,
                              float* __restrict__ hpart) {
  int s = blockIdx.y;
  int j = blockIdx.x * 256 + threadIdx.x;
  int k0 = s * 32;
  __shared__ float cs[NB][32];
  for (int i = threadIdx.x; i < NB * 32; i += 256)
    cs[i >> 5][i & 31] = c[(size_t)(i >> 5) * DD + k0 + (i & 31)];
  __syncthreads();
  float acc[NB];
  #pragma unroll
  for (int b = 0; b < NB; b++) acc[b] = 0.f;
  #pragma unroll
  for (int al = 0; al < 32; al++) {
    float wv = W1[(size_t)(k0 + al) * DD + j];
    #pragma unroll
    for (int b = 0; b < NB; b++) acc[b] += cs[b][al] * wv;
  }
  #pragma unroll
  for (int b = 0; b < NB; b++)
    hpart[((size_t)s * NB + b) * DD + j] = acc[b];
}

// ------- h = gelu(sum_s hpart[s] + bias1) -------
__launch_bounds__(256)
__global__ void h_reduce_kernel(const float* __restrict__ hpart, const float* __restrict__ bias1,
                                float* __restrict__ h) {
  int idx = blockIdx.x * 256 + threadIdx.x;
  int j = idx & (DD - 1);
  float acc = bias1[j];
  #pragma unroll
  for (int s = 0; s < HSPLIT; s++) acc += hpart[(size_t)s * NB * DD + idx];
  h[idx] = gelu_f(acc);
}

// ------- w partials (bf16): float4 columns/thread, LDS-staged W2, 8 k-splits -------
#define WSTAGE(ST, BUF) do { int kr_ = k0 + (ST) * 4;                                  \
    _Pragma("unroll")                                                                  \
    for (int c_ = 0; c_ < 4; c_++)                                                     \
      gload_lds16f(W2 + (size_t)(kr_ + c_) * 32768 + j0 + t * 4,                       \
                   &wlds[BUF][c_][t * 4]);                                             \
  } while (0)

__launch_bounds__(256)
__global__ void w_part_kernel(const float* __restrict__ h, const float* __restrict__ W2,
                              u16* __restrict__ part) {
  int s = blockIdx.y;               // 0..7
  int j0 = blockIdx.x * 1024;       // f32 col base, grid.x = 32
  int k0 = s * 128;
  int t = threadIdx.x;
  __shared__ __align__(16) float wlds[2][4][1024];   // 32 KB, double-buffered (4 rows/tile)
  __shared__ __align__(16) float hlT[128][17];       // 8.7 KB, h slice [kk][b], pad 17

  #pragma unroll
  for (int v = 0; v < 8; v++) {
    int i = t + v * 256;            // b = i>>7 (0..15), kk = i&127
    hlT[i & 127][i >> 7] = h[(size_t)(i >> 7) * DD + k0 + (i & 127)];
  }

  WSTAGE(0, 0);
  WSTAGE(1, 1);

  f32x4 acc[NB];
  #pragma unroll
  for (int b = 0; b < NB; b++) acc[b] = f32x4{0.f, 0.f, 0.f, 0.f};

  #pragma unroll 1
  for (int st = 0; st < 32; st++) {
    if (st < 31) { VMCNT4; } else { VMCNT0; }
    BARRIER;
    int buf = st & 1;
    #pragma unroll
    for (int r = 0; r < 4; r++) {
      f32x4 wv = *(const f32x4*)&wlds[buf][r][t * 4];
      int kk = st * 4 + r;
      f32x4 h0 = *(const f32x4*)&hlT[kk][0];
      f32x4 h1 = *(const f32x4*)&hlT[kk][4];
      f32x4 h2 = *(const f32x4*)&hlT[kk][8];
      f32x4 h3 = *(const f32x4*)&hlT[kk][12];
      #pragma unroll
      for (int q = 0; q < 4; q++) {
        acc[q]      += h0[q] * wv;
        acc[q + 4]  += h1[q] * wv;
        acc[q + 8]  += h2[q] * wv;
        acc[q + 12] += h3[q] * wv;
      }
    }
    BARRIER;
    if (st + 2 < 32) WSTAGE(st + 2, buf);
  }

  int j4 = blockIdx.x * 256 + t;    // float4-group column index
  #pragma unroll
  for (int b = 0; b < NB; b++) {
    short4v pv;
    #pragma unroll
    for (int e = 0; e < 4; e++) pv[e] = (short)f2bf(acc[b][e]);
    *(short4v*)(part + ((size_t)s * NB + b) * 32768 + j4 * 4) = pv;
  }
}

// ---- pack_lora: inline w-reduce (bf16 partials, f32 accum) -> factor panel in LDS,
//      then aext = zero-pad8(src @ colfactor), bext = zero-pad8(rowfactor) ----
__launch_bounds__(256)
__global__ void pack_lora_kernel(const u16* __restrict__ src, const u16* __restrict__ part,
                                 const float* __restrict__ bias2, int aoff, int boff,
                                 u16* __restrict__ aext, u16* __restrict__ bext) {
  int b = blockIdx.y;
  int t = threadIdx.x;
  int off = (blockIdx.x < 16) ? aoff : boff;   // multiple of 4 elements
  __shared__ __align__(16) float fac[8192];
  {
    const f32x4* bz = (const f32x4*)(bias2 + off);
    #pragma unroll
    for (int i4 = t; i4 < 2048; i4 += 256) {
      f32x4 acc = bz[i4];
      #pragma unroll
      for (int s = 0; s < WSPLIT; s++) {
        short4v pv = *(const short4v*)(part + ((size_t)s * NB + b) * 32768 + off + i4 * 4);
        #pragma unroll
        for (int e = 0; e < 4; e++) acc[e] += bf2f((u16)pv[e]);
      }
      *(f32x4*)&fac[i4 * 4] = acc;
    }
  }
  __syncthreads();
  short8 z = {};
  if (blockIdx.x < 16) {
    int row = blockIdx.x * 64 + (t >> 2);
    int q = t & 3;
    const u16* xr = src + ((size_t)b << 20) + (size_t)row * DD + q * 256;
    float acc[8] = {};
    #pragma unroll 2
    for (int kk = 0; kk < 32; kk++) {
      short8 xv = *(const short8*)(xr + kk * 8);
      #pragma unroll
      for (int e = 0; e < 8; e++) {
        float xf = bf2f((u16)xv[e]);
        int d = q * 256 + kk * 8 + e;
        f32x4 f0 = *(const f32x4*)&fac[d * 8];
        f32x4 f1 = *(const f32x4*)&fac[d * 8 + 4];
        acc[0] += xf * f0[0]; acc[1] += xf * f0[1];
        acc[2] += xf * f0[2]; acc[3] += xf * f0[3];
        acc[4] += xf * f1[0]; acc[5] += xf * f1[1];
        acc[6] += xf * f1[2]; acc[7] += xf * f1[3];
      }
    }
    #pragma unroll
    for (int r = 0; r < 8; r++) {
      acc[r] += __shfl_xor(acc[r], 1);
      acc[r] += __shfl_xor(acc[r], 2);
    }
    short8 ov = z;
    if (q == 0) {
      #pragma unroll
      for (int r = 0; r < 8; r++) ov[r] = (short)f2bf(acc[r]);
    }
    u16* orow = aext + ((size_t)b * 1024 + row) * 64 + q * 16;
    *(short8*)orow = ov;
    *(short8*)(orow + 8) = z;
  } else {
    for (int l = t; l < 1024; l += 256) {
      short8 ov;
      #pragma unroll
      for (int r = 0; r < 8; r++) ov[r] = (short)f2bf(fac[l * 8 + r]);
      u16* orow = bext + ((size_t)b * 1024 + l) * 64;
      *(short8*)orow = ov;
      #pragma unroll
      for (int k = 1; k < 8; k++) *(short8*)(orow + k * 8) = z;
    }
  }
}

// ------- batched GEMM 128x128 tile, 4 waves, m97 structure: single-buffer LDS,
// vmcnt(0)+barrier per K-tile, 4 blocks/CU residency.  16x16x32 MFMA, K=1024+64.
#define STAGE_A(KT) do { int kt_ = (KT);                                               \
    if (kt_ < 16) { int ks_ = kt_ * 64;                                                \
      _Pragma("unroll")                                                                \
      for (int c_ = 0; c_ < 4; c_++)                                                   \
        gload_lds16(Ab + (size_t)srow[c_] * DD + ks_ + se[c_], As + ldsel[c_]);        \
    } else {                                                                           \
      _Pragma("unroll")                                                                \
      for (int c_ = 0; c_ < 4; c_++)                                                   \
        gload_lds16(Ae + (size_t)srow[c_] * 64 + se[c_], As + ldsel[c_]);              \
    } } while (0)
#define STAGE_B(KT) do { int kt_ = (KT);                                               \
    if (kt_ < 16) { int ks_ = kt_ * 64;                                                \
      _Pragma("unroll")                                                                \
      for (int c_ = 0; c_ < 4; c_++)                                                   \
        gload_lds16(Bb + (size_t)srow[c_] * DD + ks_ + se[c_], Bs + ldsel[c_]);        \
    } else {                                                                           \
      _Pragma("unroll")                                                                \
      for (int c_ = 0; c_ < 4; c_++)                                                   \
        gload_lds16(Be + (size_t)srow[c_] * 64 + se[c_], Bs + ldsel[c_]);              \
    } } while (0)

template<int PHASE>
__launch_bounds__(256, 4)
__global__ void gemm128_kernel(const u16* __restrict__ A, const u16* __restrict__ BT,
                               const u16* __restrict__ Aext, const u16* __restrict__ Bext,
                               const u16* __restrict__ resid, void* __restrict__ Cout) {
  constexpr int BK = 64;
  constexpr int NT = 17;
  __shared__ __align__(16) u16 As[128 * BK];   // 16 KB
  __shared__ __align__(16) u16 Bs[128 * BK];   // 16 KB  (32 KB total -> 4 blocks/CU)

  // Half-batch mapping: each XCD owns one 4tm x 8tn half-batch per round.
  int orig = blockIdx.x;
  int xcd = orig & 7, w = orig >> 3;
  int hb = (w >> 5) * 8 + xcd;
  int tile = w & 31;
  int b = hb >> 1;
  int tm = (hb & 1) * 4 + (tile >> 3);
  int tn = tile & 7;

  const u16* Ab = A + ((size_t)b << 20) + (size_t)(tm * 128) * DD;
  const u16* Bb = BT + (size_t)(tn * 128) * DD;                       // batch-shared
  const u16* Ae = Aext + ((size_t)b * 1024 + tm * 128) * 64;
  const u16* Be = Bext + ((size_t)b * 1024 + tn * 128) * 64;

  int t = threadIdx.x, lane = t & 63, g = lane >> 4, l15 = lane & 15;
  int wave = t >> 6;
  int wm = wave >> 1, wn = wave & 1;           // per-wave 64 x 64 output

  int srow[4], se[4], ldsel[4];
  #pragma unroll
  for (int c = 0; c < 4; c++) {
    int chunk = c * 256 + t;            // 0..1023 -> 16 KB per operand
    srow[c] = chunk >> 3;               // row 0..127
    se[c] = ((chunk & 7) ^ (srow[c] & 7)) << 3;
    ldsel[c] = chunk * 8;
  }

  f32x4 acc[4][4] = {};

  #pragma unroll 1
  for (int kt = 0; kt < NT; kt++) {
    STAGE_A(kt); STAGE_B(kt);
    VMCNT0;
    BARRIER;
    #pragma unroll
    for (int kk = 0; kk < 2; kk++) {
      short8 af[4], bf[4];
      #pragma unroll
      for (int i = 0; i < 4; i++) {
        int r = wm * 64 + i * 16 + l15;
        int e = (kk * 32 + g * 8) ^ ((r & 7) << 3);
        af[i] = *(const short8*)(As + r * BK + e);
      }
      #pragma unroll
      for (int j = 0; j < 4; j++) {
        int r = wn * 64 + j * 16 + l15;
        int e = (kk * 32 + g * 8) ^ ((r & 7) << 3);
        bf[j] = *(const short8*)(Bs + r * BK + e);
      }
      __builtin_amdgcn_s_setprio(1);
      #pragma unroll
      for (int i = 0; i < 4; i++)
        #pragma unroll
        for (int j = 0; j < 4; j++)
          acc[i][j] = __builtin_amdgcn_mfma_f32_16x16x32_bf16(af[i], bf[j], acc[i][j], 0, 0, 0);
      __builtin_amdgcn_s_setprio(0);
    }
    BARRIER;   // all waves' LDS reads done -> safe to overwrite next iteration
  }

  int r0 = tm * 128 + wm * 64, c0 = tn * 128 + wn * 64;
  if (PHASE == 1) {
    u16* mid = (u16*)Cout + ((size_t)b << 20);
    #pragma unroll
    for (int i = 0; i < 4; i++)
      #pragma unroll
      for (int j = 0; j < 4; j++)
        #pragma unroll
        for (int r = 0; r < 4; r++) {
          int row = r0 + i * 16 + g * 4 + r;
          int col = c0 + j * 16 + l15;
          mid[(size_t)row * DD + col] = f2bf(gelu_f(acc[i][j][r]));
        }
  } else {
    float* out = (float*)Cout + ((size_t)b << 20);
    const u16* xb = resid + ((size_t)b << 20);
    #pragma unroll
    for (int i = 0; i < 4; i++)
      #pragma unroll
      for (int j = 0; j < 4; j++)
        #pragma unroll
        for (int r = 0; r < 4; r++) {
          int row = r0 + i * 16 + g * 4 + r;
          int col = c0 + j * 16 + l15;
          size_t idx = (size_t)row * DD + col;
          out[idx] = bf2f(xb[idx]) + acc[i][j][r];
        }
  }
}

extern "C" void kernel_launch(void* const* d_in, const int* in_sizes, int n_in,
                              void* d_out, int out_size, void* d_ws, size_t ws_size,
                              hipStream_t stream) {
  const float* x         = (const float*)d_in[0];
  const float* ada       = (const float*)d_in[1];
  const float* base_up   = (const float*)d_in[2];
  const float* base_down = (const float*)d_in[3];
  const float* gamma     = (const float*)d_in[4];
  const float* beta      = (const float*)d_in[5];
  const float* W1        = (const float*)d_in[6];
  const float* bias1     = (const float*)d_in[7];
  const float* W2        = (const float*)d_in[8];
  const float* bias2     = (const float*)d_in[9];
  float* out = (float*)d_out;
  char* ws = (char*)d_ws;

  float* c     = (float*)(ws);                 // 64 KB
  float* h     = (float*)(ws + 0x10000);       // 64 KB
  u16*   bdTb  = (u16*)  (ws + 0x220000);      // 2 MB
  u16*   bub   = (u16*)  (ws + 0x420000);      // 2 MB
  float* hpart = (float*)(ws + 0x620000);      // 2 MB
  u16*   xb    = (u16*)  (ws + 0x820000);      // 32 MB
  u16*   uext  = (u16*)  (ws + 0x2820000);     // 2 MB
  u16*   b2ext = (u16*)  (ws + 0x2A20000);     // 2 MB
  u16*   vext  = (u16*)  (ws + 0x2C20000);     // 2 MB
  u16*   a1ext = (u16*)  (ws + 0x2E20000);     // 2 MB
  u16*   mid   = (u16*)  (ws + 0x3020000);     // 32 MB
  u16*   part  = (u16*)  (ws + 0x5020000);     // 8 MB (bf16 partials)

  prep_kernel<<<dim3(9744), dim3(256), 0, stream>>>(x, xb, ada, gamma, beta, c,
                                                    base_down, bdTb, base_up, bub);
  h_part_kernel<<<dim3(4, HSPLIT), dim3(256), 0, stream>>>(c, W1, hpart);
  h_reduce_kernel<<<dim3(64), dim3(256), 0, stream>>>(hpart, bias1, h);
  w_part_kernel<<<dim3(32, WSPLIT), dim3(256), 0, stream>>>(h, W2, part);
  pack_lora_kernel<<<dim3(17, 16), dim3(256), 0, stream>>>(xb, part, bias2, 16384, 24576,
                                                           uext, b2ext);
  gemm128_kernel<1><<<dim3(1024), dim3(256), 0, stream>>>(xb, bdTb, uext, b2ext,
                                                          (const u16*)nullptr, (void*)mid);
  pack_lora_kernel<<<dim3(17, 16), dim3(256), 0, stream>>>(mid, part, bias2, 8192, 0,
                                                           vext, a1ext);
  gemm128_kernel<2><<<dim3(1024), dim3(256), 0, stream>>>(mid, bub, vext, a1ext, xb, (void*)out);
}